// Round 1
// baseline (542.250 us; speedup 1.0000x reference)
//
#include <hip/hip_runtime.h>

// Problem constants
constexpr int Bn = 8;       // batch
constexpr int Cn = 512;     // channels
constexpr int Ln = 1024;    // H*W
constexpr int Gn = 32;      // groups
constexpr int CPG = 16;     // channels per group
constexpr float EPSv = 1e-5f;

#define TID ((int)threadIdx.x)

// ---------------- GroupNorm: one block per (b, group) ----------------
__global__ __launch_bounds__(256) void gn_kernel(
    const float* __restrict__ x, const float* __restrict__ gamma,
    const float* __restrict__ beta, float* __restrict__ xn) {
  int blk = blockIdx.x;
  int b = blk >> 5, g = blk & 31;
  size_t base = ((size_t)(b * Cn + g * CPG)) * Ln;
  const float4* xp4 = (const float4*)(x + base);
  float s = 0.f, ss = 0.f;
#pragma unroll
  for (int i = 0; i < 16; ++i) {
    float4 v = xp4[TID + i * 256];
    s += v.x + v.y + v.z + v.w;
    ss += v.x * v.x + v.y * v.y + v.z * v.z + v.w * v.w;
  }
#pragma unroll
  for (int off = 32; off; off >>= 1) {
    s += __shfl_down(s, off);
    ss += __shfl_down(ss, off);
  }
  __shared__ float sm[4], ssm[4];
  int wv = TID >> 6;
  if ((TID & 63) == 0) { sm[wv] = s; ssm[wv] = ss; }
  __syncthreads();
  float tot = sm[0] + sm[1] + sm[2] + sm[3];
  float tots = ssm[0] + ssm[1] + ssm[2] + ssm[3];
  float mean = tot * (1.f / 16384.f);
  float var = tots * (1.f / 16384.f) - mean * mean;
  float rstd = rsqrtf(var + EPSv);
  float4* o4 = (float4*)(xn + base);
#pragma unroll
  for (int i = 0; i < 16; ++i) {
    int idx = TID + i * 256;
    int c = g * CPG + (idx >> 8);  // idx*4/1024
    float ga = gamma[c] * rstd;
    float be = beta[c];
    float4 v = xp4[idx];
    float4 o;
    o.x = (v.x - mean) * ga + be;
    o.y = (v.y - mean) * ga + be;
    o.z = (v.z - mean) * ga + be;
    o.w = (v.w - mean) * ga + be;
    o4[idx] = o;
  }
}

// ---------------- fp32 tiled GEMM: C[b,m,n] = sum_k A[m,k]*B[b,k,n] (+bias, +resid) ----
// tile 64x64, K-step 16, 256 threads, 4x4 per thread
template <int MT, bool RESID>
__global__ __launch_bounds__(256) void gemm_kernel(
    const float* __restrict__ A, const float* __restrict__ Bm,
    const float* __restrict__ bias, const float* __restrict__ resid,
    float* __restrict__ Cout) {
  __shared__ float As[16][68];
  __shared__ float Bs[16][68];
  int m0 = blockIdx.x * 64, n0 = blockIdx.y * 64;
  int b = blockIdx.z;
  const float* Bb = Bm + (size_t)b * Cn * Ln;
  int tx = TID & 15, ty = TID >> 4;
  float acc[4][4] = {};
  int amr = TID >> 2, akk = (TID & 3) * 4;
  int bkr = TID >> 4, bnn = (TID & 15) * 4;
  for (int k0 = 0; k0 < Cn; k0 += 16) {
    float4 a4 = *(const float4*)&A[(size_t)(m0 + amr) * Cn + k0 + akk];
    float4 b4 = *(const float4*)&Bb[(size_t)(k0 + bkr) * Ln + n0 + bnn];
    As[akk + 0][amr] = a4.x;
    As[akk + 1][amr] = a4.y;
    As[akk + 2][amr] = a4.z;
    As[akk + 3][amr] = a4.w;
    *(float4*)&Bs[bkr][bnn] = b4;
    __syncthreads();
#pragma unroll
    for (int k = 0; k < 16; ++k) {
      float4 av = *(const float4*)&As[k][ty * 4];
      float4 bv = *(const float4*)&Bs[k][tx * 4];
      float aa[4] = {av.x, av.y, av.z, av.w};
      float bb[4] = {bv.x, bv.y, bv.z, bv.w};
#pragma unroll
      for (int i = 0; i < 4; ++i)
#pragma unroll
        for (int j = 0; j < 4; ++j) acc[i][j] += aa[i] * bb[j];
    }
    __syncthreads();
  }
#pragma unroll
  for (int i = 0; i < 4; ++i) {
    int m = m0 + ty * 4 + i;
    float bi = bias[m];
    size_t rowoff = ((size_t)b * MT + m) * Ln + n0 + tx * 4;
    float4 o;
    o.x = acc[i][0] + bi;
    o.y = acc[i][1] + bi;
    o.z = acc[i][2] + bi;
    o.w = acc[i][3] + bi;
    if (RESID) {
      float4 r = *(const float4*)&resid[((size_t)b * Cn + m) * Ln + n0 + tx * 4];
      o.x += r.x; o.y += r.y; o.z += r.z; o.w += r.w;
    }
    *(float4*)&Cout[rowoff] = o;
  }
}

// ---------------- flash attention: block = (q-tile of 64, head) ----------------
__global__ __launch_bounds__(256) void attn_kernel(const float* __restrict__ qkv,
                                                   float* __restrict__ abuf) {
  __shared__ float Qs[64][68], Ks[64][68], Vst[64][68], Pst[64][68];
  __shared__ float m_s[64], l_s[64], al_s[64];
  int t0 = blockIdx.x * 64;
  int bh = blockIdx.y;
  int b = bh >> 3, h = bh & 7;
  const float* qp = qkv + (size_t)b * 1536 * Ln + (size_t)(h * 64) * Ln;
  const float* kp = qp + (size_t)512 * Ln;
  const float* vp = qp + (size_t)1024 * Ln;
  int tx = TID & 15, ty = TID >> 4;
  // load Q tile: Qs[c][t]
#pragma unroll
  for (int it = 0; it < 4; ++it) {
    int idx = it * 256 + TID;
    int c = idx >> 4, tq = (idx & 15) * 4;
    *(float4*)&Qs[c][tq] = *(const float4*)&qp[(size_t)c * Ln + t0 + tq];
  }
  if (TID < 64) { m_s[TID] = -1e30f; l_s[TID] = 0.f; }
  float o[4][4] = {};  // o[i][j]: t = tx*4+i, c = ty*4+j
  for (int s0 = 0; s0 < Ln; s0 += 64) {
    __syncthreads();
    // load K tile (Ks[c][s]) and V tile transposed (Vst[s][c])
#pragma unroll
    for (int it = 0; it < 4; ++it) {
      int idx = it * 256 + TID;
      int c = idx >> 4, sq = (idx & 15) * 4;
      *(float4*)&Ks[c][sq] = *(const float4*)&kp[(size_t)c * Ln + s0 + sq];
      float4 v4 = *(const float4*)&vp[(size_t)c * Ln + s0 + sq];
      Vst[sq + 0][c] = v4.x;
      Vst[sq + 1][c] = v4.y;
      Vst[sq + 2][c] = v4.z;
      Vst[sq + 3][c] = v4.w;
    }
    __syncthreads();
    // QK^T -> S[s][t]; thread: s = ty*4+i, t = tx*4+j
    float acc[4][4] = {};
#pragma unroll
    for (int c = 0; c < 64; ++c) {
      float4 q4 = *(const float4*)&Qs[c][tx * 4];
      float4 k4 = *(const float4*)&Ks[c][ty * 4];
      float qa[4] = {q4.x, q4.y, q4.z, q4.w};
      float ka[4] = {k4.x, k4.y, k4.z, k4.w};
#pragma unroll
      for (int i = 0; i < 4; ++i)
#pragma unroll
        for (int j = 0; j < 4; ++j) acc[i][j] += ka[i] * qa[j];
    }
#pragma unroll
    for (int i = 0; i < 4; ++i) {
      float4 w4;
      w4.x = acc[i][0] * 0.125f;
      w4.y = acc[i][1] * 0.125f;
      w4.z = acc[i][2] * 0.125f;
      w4.w = acc[i][3] * 0.125f;
      *(float4*)&Pst[ty * 4 + i][tx * 4] = w4;  // Pst[s][t]
    }
    __syncthreads();
    // online softmax per query row t (serial per lane; conflict-free column scan)
    if (TID < 64) {
      int t = TID;
      float mo = m_s[t];
      float mx = mo;
      for (int s = 0; s < 64; ++s) mx = fmaxf(mx, Pst[s][t]);
      float alpha = __expf(mo - mx);
      float l = l_s[t] * alpha;
      for (int s = 0; s < 64; ++s) {
        float p = __expf(Pst[s][t] - mx);
        Pst[s][t] = p;
        l += p;
      }
      m_s[t] = mx; l_s[t] = l; al_s[t] = alpha;
    }
    __syncthreads();
    float al[4];
#pragma unroll
    for (int i = 0; i < 4; ++i) al[i] = al_s[tx * 4 + i];
#pragma unroll
    for (int i = 0; i < 4; ++i)
#pragma unroll
      for (int j = 0; j < 4; ++j) o[i][j] *= al[i];
    // PV: o[t][c] += sum_s P[t][s] * V[c][s]
#pragma unroll 8
    for (int s = 0; s < 64; ++s) {
      float4 p4 = *(const float4*)&Pst[s][tx * 4];
      float4 v4 = *(const float4*)&Vst[s][ty * 4];
      float pa[4] = {p4.x, p4.y, p4.z, p4.w};
      float va[4] = {v4.x, v4.y, v4.z, v4.w};
#pragma unroll
      for (int i = 0; i < 4; ++i)
#pragma unroll
        for (int j = 0; j < 4; ++j) o[i][j] += pa[i] * va[j];
    }
  }
  // epilogue: a[bh][c][t] = o / l
  float rl[4];
#pragma unroll
  for (int i = 0; i < 4; ++i) rl[i] = 1.f / l_s[tx * 4 + i];
  float* ap = abuf + (size_t)bh * 64 * Ln;
#pragma unroll
  for (int i = 0; i < 4; ++i)
#pragma unroll
    for (int j = 0; j < 4; ++j) {
      int t = tx * 4 + i, c = ty * 4 + j;
      ap[(size_t)c * Ln + t0 + t] = o[i][j] * rl[i];
    }
}

extern "C" void kernel_launch(void* const* d_in, const int* in_sizes, int n_in,
                              void* d_out, int out_size, void* d_ws, size_t ws_size,
                              hipStream_t stream) {
  const float* x = (const float*)d_in[0];
  const float* gamma = (const float*)d_in[1];
  const float* beta = (const float*)d_in[2];
  const float* w_qkv = (const float*)d_in[3];
  const float* b_qkv = (const float*)d_in[4];
  const float* w_proj = (const float*)d_in[5];
  const float* b_proj = (const float*)d_in[6];
  float* out = (float*)d_out;
  float* ws = (float*)d_ws;

  // xn goes in d_out (scratch; fully overwritten by proj at the end)
  float* xn = out;
  float* qkv = ws;                        // 8*1536*1024 floats = 48 MB
  float* abuf = ws + (size_t)Bn * 1536 * Ln;  // 8*512*1024 floats = 16 MB

  gn_kernel<<<dim3(Bn * Gn), dim3(256), 0, stream>>>(x, gamma, beta, xn);

  gemm_kernel<1536, false><<<dim3(1536 / 64, Ln / 64, Bn), dim3(256), 0, stream>>>(
      w_qkv, xn, b_qkv, nullptr, qkv);

  attn_kernel<<<dim3(Ln / 64, Bn * 8), dim3(256), 0, stream>>>(qkv, abuf);

  gemm_kernel<512, true><<<dim3(512 / 64, Ln / 64, Bn), dim3(256), 0, stream>>>(
      w_proj, abuf, b_proj, x, out);
}

// Round 2
// 151.415 us; speedup vs baseline: 3.5812x; 3.5812x over previous
//
#include <hip/hip_runtime.h>

typedef unsigned short u16;
using bf16x8 = __attribute__((ext_vector_type(8))) __bf16;
using f32x4  = __attribute__((ext_vector_type(4))) float;
using u16x8  = __attribute__((ext_vector_type(8))) u16;

#define TID ((int)threadIdx.x)

__device__ __forceinline__ u16 f2bf(float f) {
  union { float f; unsigned u; } v; v.f = f;
  unsigned r = (v.u + 0x7fffu + ((v.u >> 16) & 1u)) >> 16;
  return (u16)r;
}
__device__ __forceinline__ bf16x8 ldfrag(const u16* p) {
  return __builtin_bit_cast(bf16x8, *(const u16x8*)p);
}
// XOR swizzle of 16B chunks within a 128B row; bijective per row, conflict-free
// for both row-consecutive b128 writes and 16-consecutive-row frag reads.
__device__ __forceinline__ int swz(int row, int ch) {
  return ch ^ (row & 7) ^ ((row >> 3) & 7);
}
__device__ __forceinline__ f32x4 mfma16(bf16x8 a, bf16x8 b, f32x4 c) {
  return __builtin_amdgcn_mfma_f32_16x16x32_bf16(a, b, c, 0, 0, 0);
}

// ---------------- GroupNorm pass 1: per-(b,g) mean/rstd ----------------
__global__ __launch_bounds__(256) void gn_stats(const float* __restrict__ x,
                                                float* __restrict__ stats) {
  size_t base = ((size_t)blockIdx.x) << 14;  // (b*32+g)*16384
  const float4* xp = (const float4*)(x + base);
  float s = 0.f, ss = 0.f;
#pragma unroll
  for (int i = 0; i < 16; ++i) {
    float4 v = xp[TID + i * 256];
    s += v.x + v.y + v.z + v.w;
    ss += v.x * v.x + v.y * v.y + v.z * v.z + v.w * v.w;
  }
#pragma unroll
  for (int off = 32; off; off >>= 1) {
    s += __shfl_down(s, off);
    ss += __shfl_down(ss, off);
  }
  __shared__ float sm[4], ssm[4];
  if ((TID & 63) == 0) { sm[TID >> 6] = s; ssm[TID >> 6] = ss; }
  __syncthreads();
  if (TID == 0) {
    float tot = sm[0] + sm[1] + sm[2] + sm[3];
    float tots = ssm[0] + ssm[1] + ssm[2] + ssm[3];
    float mean = tot * (1.f / 16384.f);
    float var = tots * (1.f / 16384.f) - mean * mean;
    stats[blockIdx.x * 2] = mean;
    stats[blockIdx.x * 2 + 1] = rsqrtf(var + 1e-5f);
  }
}

// ---------------- GroupNorm pass 2: normalize + transpose -> xnT[b][l][c] bf16 ----
__global__ __launch_bounds__(256) void gn_apply(
    const float* __restrict__ x, const float* __restrict__ gamma,
    const float* __restrict__ beta, const float* __restrict__ stats,
    u16* __restrict__ xnT) {
  __shared__ u16 xt[32 * 520];  // [l][c], stride 520 breaks bank alignment
  int l0 = blockIdx.x * 32, b = blockIdx.y;
  int li = TID & 31, cb = TID >> 5;
#pragma unroll 4
  for (int it = 0; it < 64; ++it) {
    int c = it * 8 + cb;
    int g = c >> 4;
    float mean = stats[(b * 32 + g) * 2];
    float rstd = stats[(b * 32 + g) * 2 + 1];
    float ga = gamma[c] * rstd;
    float be = beta[c] - mean * ga;
    float v = x[((size_t)b * 512 + c) * 1024 + l0 + li];
    xt[li * 520 + c] = f2bf(v * ga + be);
  }
  __syncthreads();
  int li2 = TID >> 3, u0 = TID & 7;
#pragma unroll
  for (int it = 0; it < 8; ++it) {
    int unit = u0 + it * 8;
    u16x8 v = *(const u16x8*)&xt[li2 * 520 + unit * 8];
    *(u16x8*)&xnT[((size_t)b * 1024 + l0 + li2) * 512 + unit * 8] = v;
  }
}

// ---------------- weight fp32 -> bf16 prep ----------------
__global__ __launch_bounds__(256) void prep_w(const float* __restrict__ wq,
                                              const float* __restrict__ wp,
                                              u16* __restrict__ wqb,
                                              u16* __restrict__ wpb) {
  int i = blockIdx.x * 256 + TID;
  if (i < 196608) {
    float4 v = ((const float4*)wq)[i];
    u16* o = wqb + i * 4;
    o[0] = f2bf(v.x); o[1] = f2bf(v.y); o[2] = f2bf(v.z); o[3] = f2bf(v.w);
  } else {
    int j = i - 196608;
    float4 v = ((const float4*)wp)[j];
    u16* o = wpb + j * 4;
    o[0] = f2bf(v.x); o[1] = f2bf(v.y); o[2] = f2bf(v.z); o[3] = f2bf(v.w);
  }
}

// ---------------- bf16 MFMA GEMM: C[b][m][n] = A[m][:] . Bt[b][n][:] ----------------
// A [MA][512] bf16 row-major, Bt [b][1024][512] bf16 (k-contiguous rows).
// MODE 0 (qkv): out bf16 [b][1536][1024], rows<512 scaled 0.125 (attn q-scale).
// MODE 1 (proj): out fp32 [b][512][1024] = acc + bias + resid.
template <int MODE>
__global__ __launch_bounds__(256) void mfma_gemm(
    const u16* __restrict__ A, const u16* __restrict__ Bt,
    const float* __restrict__ bias, const float* __restrict__ resid,
    u16* __restrict__ obf, float* __restrict__ of) {
  __shared__ u16 Al[128 * 64], Bl[128 * 64];
  int m0 = blockIdx.x * 128, n0 = blockIdx.y * 128, b = blockIdx.z;
  int lane = TID & 63, w = TID >> 6;
  int mw = (w >> 1) * 64, nw = (w & 1) * 64;
  const u16* Bb = Bt + ((size_t)b) * 1024 * 512;
  f32x4 acc[4][4] = {};
  for (int k0 = 0; k0 < 512; k0 += 64) {
#pragma unroll
    for (int u = 0; u < 4; ++u) {
      int unit = u * 256 + TID;
      int row = unit >> 3, ch = unit & 7;
      u16x8 av = *(const u16x8*)&A[(size_t)(m0 + row) * 512 + k0 + ch * 8];
      u16x8 bv = *(const u16x8*)&Bb[(size_t)(n0 + row) * 512 + k0 + ch * 8];
      *(u16x8*)&Al[row * 64 + swz(row, ch) * 8] = av;
      *(u16x8*)&Bl[row * 64 + swz(row, ch) * 8] = bv;
    }
    __syncthreads();
    bf16x8 af[4][2];
#pragma unroll
    for (int mi = 0; mi < 4; ++mi)
#pragma unroll
      for (int kf = 0; kf < 2; ++kf) {
        int row = mw + mi * 16 + (lane & 15);
        int lc = kf * 4 + (lane >> 4);
        af[mi][kf] = ldfrag(&Al[row * 64 + swz(row, lc) * 8]);
      }
#pragma unroll
    for (int ni = 0; ni < 4; ++ni) {
      int row = nw + ni * 16 + (lane & 15);
      int lc = lane >> 4;
      bf16x8 b0 = ldfrag(&Bl[row * 64 + swz(row, lc) * 8]);
      bf16x8 b1 = ldfrag(&Bl[row * 64 + swz(row, lc + 4) * 8]);
#pragma unroll
      for (int mi = 0; mi < 4; ++mi) {
        acc[mi][ni] = mfma16(af[mi][0], b0, acc[mi][ni]);
        acc[mi][ni] = mfma16(af[mi][1], b1, acc[mi][ni]);
      }
    }
    __syncthreads();
  }
#pragma unroll
  for (int mi = 0; mi < 4; ++mi)
#pragma unroll
    for (int ni = 0; ni < 4; ++ni)
#pragma unroll
      for (int r = 0; r < 4; ++r) {
        int o = m0 + mw + mi * 16 + (lane >> 4) * 4 + r;
        int l = n0 + nw + ni * 16 + (lane & 15);
        float v = acc[mi][ni][r] + bias[o];
        if (MODE == 0) {
          if (o < 512) v *= 0.125f;  // fold attn scale (1/8) into Q
          obf[((size_t)b * 1536 + o) * 1024 + l] = f2bf(v);
        } else {
          size_t idx = ((size_t)b * 512 + o) * 1024 + l;
          of[idx] = v + resid[idx];
        }
      }
}

// ---------------- MFMA flash attention ----------------
// Block: 64 queries (t0..t0+64) x one (b,h). 4 waves, wave owns 16 t-rows.
// qkv natural [b][1536][1024] bf16; out aT[b][l][c] bf16.
__global__ __launch_bounds__(256) void attn_mfma(const u16* __restrict__ qkv,
                                                 u16* __restrict__ aT) {
  __shared__ u16 Qs[4096], Ks[4096], Vs[4096], Ps[4096];
  int t0 = blockIdx.x * 64;
  int bh = blockIdx.y, b = bh >> 3, h = bh & 7;
  const u16* qp = qkv + ((size_t)b * 1536 + h * 64) * 1024;
  const u16* kp = qp + 512 * 1024;
  const u16* vp = qp + 1024 * 1024;
  int lane = TID & 63, w = TID >> 6;
  // stage Q^T: Qs[t][c] (swizzled)
#pragma unroll
  for (int u = 0; u < 2; ++u) {
    int unit = u * 256 + TID;
    int c = unit >> 3, tch = unit & 7;
    u16x8 v = *(const u16x8*)&qp[(size_t)c * 1024 + t0 + tch * 8];
#pragma unroll
    for (int j = 0; j < 8; ++j) {
      int t = tch * 8 + j;
      Qs[t * 64 + swz(t, c >> 3) * 8 + (c & 7)] = v[j];
    }
  }
  __syncthreads();
  bf16x8 qf[2];
#pragma unroll
  for (int kf = 0; kf < 2; ++kf) {
    int row = w * 16 + (lane & 15);
    int lc = kf * 4 + (lane >> 4);
    qf[kf] = ldfrag(&Qs[row * 64 + swz(row, lc) * 8]);
  }
  float m_r[4], l_r[4];
  f32x4 oacc[4] = {};
#pragma unroll
  for (int r = 0; r < 4; ++r) { m_r[r] = -1e30f; l_r[r] = 0.f; }

  for (int s0 = 0; s0 < 1024; s0 += 64) {
    __syncthreads();  // all waves done reading Ks/Vs of prev iter
    // stage K^T: Ks[s][c]; stage V natural: Vs[c][s]
#pragma unroll
    for (int u = 0; u < 2; ++u) {
      int unit = u * 256 + TID;
      int c = unit >> 3, sch = unit & 7;
      u16x8 kv = *(const u16x8*)&kp[(size_t)c * 1024 + s0 + sch * 8];
#pragma unroll
      for (int j = 0; j < 8; ++j) {
        int s = sch * 8 + j;
        Ks[s * 64 + swz(s, c >> 3) * 8 + (c & 7)] = kv[j];
      }
      u16x8 vv = *(const u16x8*)&vp[(size_t)c * 1024 + s0 + sch * 8];
      *(u16x8*)&Vs[c * 64 + swz(c, sch) * 8] = vv;
    }
    __syncthreads();
    // S = Q^T K  (rows t, cols s)
    f32x4 sacc[4] = {};
#pragma unroll
    for (int sb = 0; sb < 4; ++sb) {
      int srow = sb * 16 + (lane & 15);
      int lc = lane >> 4;
      bf16x8 kf0 = ldfrag(&Ks[srow * 64 + swz(srow, lc) * 8]);
      bf16x8 kf1 = ldfrag(&Ks[srow * 64 + swz(srow, lc + 4) * 8]);
      sacc[sb] = mfma16(qf[0], kf0, sacc[sb]);
      sacc[sb] = mfma16(qf[1], kf1, sacc[sb]);
    }
    // wave-parallel online softmax; row = (lane>>4)*4 + r of this wave's 16 t
    float mx[4];
#pragma unroll
    for (int r = 0; r < 4; ++r)
      mx[r] = fmaxf(fmaxf(sacc[0][r], sacc[1][r]), fmaxf(sacc[2][r], sacc[3][r]));
#pragma unroll
    for (int off = 1; off < 16; off <<= 1)
#pragma unroll
      for (int r = 0; r < 4; ++r) mx[r] = fmaxf(mx[r], __shfl_xor(mx[r], off));
    float al[4];
#pragma unroll
    for (int r = 0; r < 4; ++r) {
      float mn = fmaxf(m_r[r], mx[r]);
      al[r] = __expf(m_r[r] - mn);
      m_r[r] = mn;
    }
    float p[4][4], rs[4] = {0.f, 0.f, 0.f, 0.f};
#pragma unroll
    for (int sb = 0; sb < 4; ++sb)
#pragma unroll
      for (int r = 0; r < 4; ++r) {
        p[sb][r] = __expf(sacc[sb][r] - m_r[r]);
        rs[r] += p[sb][r];
      }
#pragma unroll
    for (int off = 1; off < 16; off <<= 1)
#pragma unroll
      for (int r = 0; r < 4; ++r) rs[r] += __shfl_xor(rs[r], off);
#pragma unroll
    for (int r = 0; r < 4; ++r) l_r[r] = l_r[r] * al[r] + rs[r];
    // write P (bf16) to wave-private LDS rows, then rescale O
#pragma unroll
    for (int sb = 0; sb < 4; ++sb)
#pragma unroll
      for (int r = 0; r < 4; ++r) {
        int t = w * 16 + (lane >> 4) * 4 + r;
        int s = sb * 16 + (lane & 15);
        Ps[t * 64 + swz(t, s >> 3) * 8 + (s & 7)] = f2bf(p[sb][r]);
      }
#pragma unroll
    for (int cf = 0; cf < 4; ++cf)
#pragma unroll
      for (int r = 0; r < 4; ++r) oacc[cf][r] *= al[r];
    // O += P V
#pragma unroll
    for (int sf = 0; sf < 2; ++sf) {
      int prow = w * 16 + (lane & 15);
      int plc = sf * 4 + (lane >> 4);
      bf16x8 pa = ldfrag(&Ps[prow * 64 + swz(prow, plc) * 8]);
#pragma unroll
      for (int cf = 0; cf < 4; ++cf) {
        int crow = cf * 16 + (lane & 15);
        bf16x8 vb = ldfrag(&Vs[crow * 64 + swz(crow, plc) * 8]);
        oacc[cf] = mfma16(pa, vb, oacc[cf]);
      }
    }
  }
  float rl[4];
#pragma unroll
  for (int r = 0; r < 4; ++r) rl[r] = 1.f / l_r[r];
#pragma unroll
  for (int cf = 0; cf < 4; ++cf)
#pragma unroll
    for (int r = 0; r < 4; ++r) {
      int t = t0 + w * 16 + (lane >> 4) * 4 + r;
      int c = h * 64 + cf * 16 + (lane & 15);
      aT[((size_t)b * 1024 + t) * 512 + c] = f2bf(oacc[cf][r] * rl[r]);
    }
}

extern "C" void kernel_launch(void* const* d_in, const int* in_sizes, int n_in,
                              void* d_out, int out_size, void* d_ws, size_t ws_size,
                              hipStream_t stream) {
  const float* x = (const float*)d_in[0];
  const float* gamma = (const float*)d_in[1];
  const float* beta = (const float*)d_in[2];
  const float* w_qkv = (const float*)d_in[3];
  const float* b_qkv = (const float*)d_in[4];
  const float* w_proj = (const float*)d_in[5];
  const float* b_proj = (const float*)d_in[6];
  float* out = (float*)d_out;

  u16* qkvb = (u16*)d_ws;                  // 8*1536*1024 = 12582912 (24 MB)
  u16* xnT = qkvb + 12582912;              // 8*1024*512 = 4194304 (8 MB)
  u16* aTb = xnT + 4194304;                // 4194304 (8 MB)
  u16* wqb = aTb + 4194304;                // 786432 (1.5 MB)
  u16* wpb = wqb + 786432;                 // 262144 (0.5 MB)
  float* stats = (float*)(wpb + 262144);   // 512 floats

  prep_w<<<dim3(1024), dim3(256), 0, stream>>>(w_qkv, w_proj, wqb, wpb);
  gn_stats<<<dim3(256), dim3(256), 0, stream>>>(x, stats);
  gn_apply<<<dim3(32, 8), dim3(256), 0, stream>>>(x, gamma, beta, stats, xnT);
  mfma_gemm<0><<<dim3(12, 8, 8), dim3(256), 0, stream>>>(wqb, xnT, b_qkv, nullptr,
                                                         qkvb, nullptr);
  attn_mfma<<<dim3(16, 64), dim3(256), 0, stream>>>(qkvb, aTb);
  mfma_gemm<1><<<dim3(4, 8, 8), dim3(256), 0, stream>>>(wpb, aTb, b_proj, x,
                                                        nullptr, out);
}

// Round 4
// 137.194 us; speedup vs baseline: 3.9524x; 1.1037x over previous
//
#include <hip/hip_runtime.h>

typedef unsigned short u16;
using bf16x8 = __attribute__((ext_vector_type(8))) __bf16;
using f32x4  = __attribute__((ext_vector_type(4))) float;
using f32x16 = __attribute__((ext_vector_type(16))) float;
using u16x8  = __attribute__((ext_vector_type(8))) u16;

constexpr float QSC = 0.180336880111112f;  // 0.125 * log2(e): softmax in exp2 domain

#define TID ((int)threadIdx.x)

__device__ __forceinline__ float fexp2(float x) {
  return exp2f(x);
}
__device__ __forceinline__ u16 f2bf(float f) {
  union { float f; unsigned u; } v; v.f = f;
  unsigned r = (v.u + 0x7fffu + ((v.u >> 16) & 1u)) >> 16;
  return (u16)r;
}
__device__ __forceinline__ unsigned pkbf(float a, float b) {
  return (unsigned)f2bf(a) | ((unsigned)f2bf(b) << 16);
}
__device__ __forceinline__ bf16x8 ldfrag(const u16* p) {
  return __builtin_bit_cast(bf16x8, *(const u16x8*)p);
}
// XOR swizzle of 16B chunks within a 128B row
__device__ __forceinline__ int swz(int row, int ch) {
  return ch ^ (row & 7) ^ ((row >> 3) & 7);
}
__device__ __forceinline__ f32x4 mfma16(bf16x8 a, bf16x8 b, f32x4 c) {
  return __builtin_amdgcn_mfma_f32_16x16x32_bf16(a, b, c, 0, 0, 0);
}
__device__ __forceinline__ f32x16 mfma32(bf16x8 a, bf16x8 b, f32x16 c) {
  return __builtin_amdgcn_mfma_f32_32x32x16_bf16(a, b, c, 0, 0, 0);
}

// ---------------- GroupNorm pass 1 ----------------
__global__ __launch_bounds__(256) void gn_stats(const float* __restrict__ x,
                                                float* __restrict__ stats) {
  size_t base = ((size_t)blockIdx.x) << 14;
  const float4* xp = (const float4*)(x + base);
  float s = 0.f, ss = 0.f;
#pragma unroll
  for (int i = 0; i < 16; ++i) {
    float4 v = xp[TID + i * 256];
    s += v.x + v.y + v.z + v.w;
    ss += v.x * v.x + v.y * v.y + v.z * v.z + v.w * v.w;
  }
#pragma unroll
  for (int off = 32; off; off >>= 1) {
    s += __shfl_down(s, off);
    ss += __shfl_down(ss, off);
  }
  __shared__ float sm[4], ssm[4];
  if ((TID & 63) == 0) { sm[TID >> 6] = s; ssm[TID >> 6] = ss; }
  __syncthreads();
  if (TID == 0) {
    float tot = sm[0] + sm[1] + sm[2] + sm[3];
    float tots = ssm[0] + ssm[1] + ssm[2] + ssm[3];
    float mean = tot * (1.f / 16384.f);
    float var = tots * (1.f / 16384.f) - mean * mean;
    stats[blockIdx.x * 2] = mean;
    stats[blockIdx.x * 2 + 1] = rsqrtf(var + 1e-5f);
  }
}

// ---------------- GroupNorm pass 2: -> xnT[b][l][c] bf16 ----------------
__global__ __launch_bounds__(256) void gn_apply(
    const float* __restrict__ x, const float* __restrict__ gamma,
    const float* __restrict__ beta, const float* __restrict__ stats,
    u16* __restrict__ xnT) {
  __shared__ u16 xt[32 * 520];
  int l0 = blockIdx.x * 32, b = blockIdx.y;
  int li = TID & 31, cb = TID >> 5;
#pragma unroll 4
  for (int it = 0; it < 64; ++it) {
    int c = it * 8 + cb;
    int g = c >> 4;
    float mean = stats[(b * 32 + g) * 2];
    float rstd = stats[(b * 32 + g) * 2 + 1];
    float ga = gamma[c] * rstd;
    float be = beta[c] - mean * ga;
    float v = x[((size_t)b * 512 + c) * 1024 + l0 + li];
    xt[li * 520 + c] = f2bf(v * ga + be);
  }
  __syncthreads();
  int li2 = TID >> 3, u0 = TID & 7;
#pragma unroll
  for (int it = 0; it < 8; ++it) {
    int unit = u0 + it * 8;
    u16x8 v = *(const u16x8*)&xt[li2 * 520 + unit * 8];
    *(u16x8*)&xnT[((size_t)b * 1024 + l0 + li2) * 512 + unit * 8] = v;
  }
}

// ---------------- weight fp32 -> bf16 ----------------
__global__ __launch_bounds__(256) void prep_w(const float* __restrict__ wq,
                                              const float* __restrict__ wp,
                                              u16* __restrict__ wqb,
                                              u16* __restrict__ wpb) {
  int i = blockIdx.x * 256 + TID;
  if (i < 196608) {
    float4 v = ((const float4*)wq)[i];
    u16* o = wqb + i * 4;
    o[0] = f2bf(v.x); o[1] = f2bf(v.y); o[2] = f2bf(v.z); o[3] = f2bf(v.w);
  } else {
    int j = i - 196608;
    float4 v = ((const float4*)wp)[j];
    u16* o = wpb + j * 4;
    o[0] = f2bf(v.x); o[1] = f2bf(v.y); o[2] = f2bf(v.z); o[3] = f2bf(v.w);
  }
}

// ---------------- bf16 MFMA GEMM over k=512 ----------------
// A [.][512] bf16, Bt [b][1024][512] bf16 (k-contiguous).
// MODE 0 (QK, transposed output): D[l][o]; Q (o<512, scaled QSC) -> qT[bh][t][c],
//          K -> kT[bh][s][c].
// MODE 1 (V): normal D[o][l] -> vb[bh][c][s] bf16.
// MODE 2 (proj): normal, fp32 out + bias + resid.
template <int MODE>
__global__ __launch_bounds__(256) void mfma_gemm(
    const u16* __restrict__ A, const u16* __restrict__ Bt,
    const float* __restrict__ bias, const float* __restrict__ resid,
    u16* __restrict__ o16a, u16* __restrict__ o16b, float* __restrict__ of) {
  __shared__ u16 Al[128 * 64], Bl[128 * 64];
  int m0 = blockIdx.x * 128, n0 = blockIdx.y * 128, b = blockIdx.z;
  int lane = TID & 63, w = TID >> 6;
  int mw = (w >> 1) * 64, nw = (w & 1) * 64;
  const u16* Bb = Bt + ((size_t)b) * 1024 * 512;
  f32x4 acc[4][4] = {};
  for (int k0 = 0; k0 < 512; k0 += 64) {
#pragma unroll
    for (int u = 0; u < 4; ++u) {
      int unit = u * 256 + TID;
      int row = unit >> 3, ch = unit & 7;
      u16x8 av = *(const u16x8*)&A[(size_t)(m0 + row) * 512 + k0 + ch * 8];
      u16x8 bv = *(const u16x8*)&Bb[(size_t)(n0 + row) * 512 + k0 + ch * 8];
      *(u16x8*)&Al[row * 64 + swz(row, ch) * 8] = av;
      *(u16x8*)&Bl[row * 64 + swz(row, ch) * 8] = bv;
    }
    __syncthreads();
    // X = A-operand rows (MODE0: l from Bl; else o from Al)
    bf16x8 xf[4][2];
#pragma unroll
    for (int xi = 0; xi < 4; ++xi)
#pragma unroll
      for (int kf = 0; kf < 2; ++kf) {
        int row = (MODE == 0 ? nw : mw) + xi * 16 + (lane & 15);
        int lc = kf * 4 + (lane >> 4);
        const u16* Xl = (MODE == 0) ? Bl : Al;
        xf[xi][kf] = ldfrag(&Xl[row * 64 + swz(row, lc) * 8]);
      }
#pragma unroll
    for (int yi = 0; yi < 4; ++yi) {
      int row = (MODE == 0 ? mw : nw) + yi * 16 + (lane & 15);
      int lc = lane >> 4;
      const u16* Yl = (MODE == 0) ? Al : Bl;
      bf16x8 y0 = ldfrag(&Yl[row * 64 + swz(row, lc) * 8]);
      bf16x8 y1 = ldfrag(&Yl[row * 64 + swz(row, lc + 4) * 8]);
#pragma unroll
      for (int xi = 0; xi < 4; ++xi) {
        acc[xi][yi] = mfma16(xf[xi][0], y0, acc[xi][yi]);
        acc[xi][yi] = mfma16(xf[xi][1], y1, acc[xi][yi]);
      }
    }
    __syncthreads();
  }
#pragma unroll
  for (int xi = 0; xi < 4; ++xi)
#pragma unroll
    for (int yi = 0; yi < 4; ++yi)
#pragma unroll
      for (int r = 0; r < 4; ++r) {
        if constexpr (MODE == 0) {
          int l = n0 + nw + xi * 16 + (lane >> 4) * 4 + r;
          int o = m0 + mw + yi * 16 + (lane & 15);
          float v = acc[xi][yi][r] + bias[o];
          if (o < 512) {
            v *= QSC;
            o16a[((size_t)(b * 8 + (o >> 6)) * 1024 + l) * 64 + (o & 63)] = f2bf(v);
          } else {
            o16b[((size_t)(b * 8 + ((o >> 6) & 7)) * 1024 + l) * 64 + (o & 63)] = f2bf(v);
          }
        } else if constexpr (MODE == 1) {
          int o = m0 + mw + xi * 16 + (lane >> 4) * 4 + r;  // local V row 0..511
          int l = n0 + nw + yi * 16 + (lane & 15);
          float v = acc[xi][yi][r] + bias[o];
          o16a[((size_t)(b * 8 + (o >> 6)) * 64 + (o & 63)) * 1024 + l] = f2bf(v);
        } else {
          int o = m0 + mw + xi * 16 + (lane >> 4) * 4 + r;
          int l = n0 + nw + yi * 16 + (lane & 15);
          size_t idx = ((size_t)b * 512 + o) * 1024 + l;
          of[idx] = acc[xi][yi][r] + bias[o] + resid[idx];
        }
      }
}

// ---------------- MFMA flash attention, 32x32, swapped operands ----------------
// Block: 128 queries x (b,h); 4 waves x 32 q-rows. Lane owns q-row t = lane&31.
__global__ __launch_bounds__(256) void attn_mfma(const u16* __restrict__ qT,
                                                 const u16* __restrict__ kT,
                                                 const u16* __restrict__ vb,
                                                 u16* __restrict__ aT) {
  __shared__ u16 smem[8192];  // Ks[64][64] | Vs[64][64]; reused as Ot[128][64]
  u16* Ks = smem;
  u16* Vs = smem + 4096;
  int t0 = blockIdx.x * 128;
  int bh = blockIdx.y, b = bh >> 3, hd = bh & 7;
  int lane = TID & 63, w = TID >> 6;
  int h = lane >> 5, ln = lane & 31;
  int t = t0 + w * 32 + ln;
  const u16* qp = qT + ((size_t)bh * 1024 + t) * 64;
  bf16x8 qf[4];
#pragma unroll
  for (int kc = 0; kc < 4; ++kc) qf[kc] = ldfrag(qp + kc * 16 + h * 8);
  float m_r = -1e30f, l_r = 0.f;
  f32x16 oacc[2] = {};

  for (int s0 = 0; s0 < 1024; s0 += 64) {
    __syncthreads();
#pragma unroll
    for (int u = 0; u < 2; ++u) {
      int unit = u * 256 + TID;
      int row = unit >> 3, ch = unit & 7;
      u16x8 kv = *(const u16x8*)&kT[((size_t)bh * 1024 + s0 + row) * 64 + ch * 8];
      *(u16x8*)&Ks[row * 64 + swz(row, ch) * 8] = kv;
      u16x8 vv = *(const u16x8*)&vb[((size_t)bh * 64 + row) * 1024 + s0 + ch * 8];
      *(u16x8*)&Vs[row * 64 + swz(row, ch) * 8] = vv;
    }
    __syncthreads();
    // S^T[s][t] = sum_c K[s][c] * Q[t][c]  (log2 units; Q pre-scaled by QSC)
    f32x16 sacc[2] = {};
#pragma unroll
    for (int sb = 0; sb < 2; ++sb) {
      int srow = sb * 32 + ln;
#pragma unroll
      for (int kc = 0; kc < 4; ++kc) {
        bf16x8 kf = ldfrag(&Ks[srow * 64 + swz(srow, kc * 2 + h) * 8]);
        sacc[sb] = mfma32(kf, qf[kc], sacc[sb]);
      }
    }
    // online softmax; lane owns row t, 32 of 64 s-values (partner = lane^32)
    float mx = sacc[0][0];
#pragma unroll
    for (int i = 1; i < 16; ++i) mx = fmaxf(mx, sacc[0][i]);
#pragma unroll
    for (int i = 0; i < 16; ++i) mx = fmaxf(mx, sacc[1][i]);
    mx = fmaxf(mx, __shfl_xor(mx, 32));
    float mn = fmaxf(m_r, mx);
    float al = fexp2(m_r - mn);
    m_r = mn;
    float rs = 0.f;
#pragma unroll
    for (int sb = 0; sb < 2; ++sb)
#pragma unroll
      for (int i = 0; i < 16; ++i) {
        float pv = fexp2(sacc[sb][i] - mn);
        sacc[sb][i] = pv;
        rs += pv;
      }
    rs += __shfl_xor(rs, 32);
    l_r = l_r * al + rs;
#pragma unroll
    for (int ca = 0; ca < 2; ++ca)
#pragma unroll
      for (int i = 0; i < 16; ++i) oacc[ca][i] *= al;
    // pack P pairs: W[sb][p4][e] = bf16x2 of s = sb*32 + 8*p4 + 4*h + 2*e (+1)
    unsigned W[2][4][2];
#pragma unroll
    for (int sb = 0; sb < 2; ++sb)
#pragma unroll
      for (int p4 = 0; p4 < 4; ++p4)
#pragma unroll
        for (int e = 0; e < 2; ++e)
          W[sb][p4][e] = pkbf(sacc[sb][p4 * 4 + 2 * e], sacc[sb][p4 * 4 + 2 * e + 1]);
    // per 16-k step m: exchange with lane^32, assemble B-frag, PV
#pragma unroll
    for (int m = 0; m < 4; ++m) {
      int sb = m >> 1, q = (m & 1) * 2;
      unsigned a0 = W[sb][q][0], a1 = W[sb][q][1];
      unsigned b0 = W[sb][q + 1][0], b1 = W[sb][q + 1][1];
      unsigned s0w = h ? a0 : b0;
      unsigned s1w = h ? a1 : b1;
      unsigned r0 = (unsigned)__shfl_xor((int)s0w, 32);
      unsigned r1 = (unsigned)__shfl_xor((int)s1w, 32);
      unsigned w0 = h ? r0 : a0;
      unsigned w1 = h ? r1 : a1;
      unsigned w2 = h ? b0 : r0;
      unsigned w3 = h ? b1 : r1;
      uint4 pw = make_uint4(w0, w1, w2, w3);
      bf16x8 pf = __builtin_bit_cast(bf16x8, pw);
#pragma unroll
      for (int ca = 0; ca < 2; ++ca) {
        int crow = ca * 32 + ln;
        bf16x8 vf = ldfrag(&Vs[crow * 64 + swz(crow, m * 2 + h) * 8]);
        oacc[ca] = mfma32(vf, pf, oacc[ca]);  // O^T[c][t]
      }
    }
  }
  // O^T -> LDS [t][c] (swizzled) -> coalesced aT[b][t][hd*64+c]
  float rl = 1.f / l_r;
  __syncthreads();
  int tloc = w * 32 + ln;
#pragma unroll
  for (int ca = 0; ca < 2; ++ca)
#pragma unroll
    for (int p4 = 0; p4 < 4; ++p4)
#pragma unroll
      for (int e = 0; e < 2; ++e) {
        int r = p4 * 4 + e * 2;
        int c = ca * 32 + 8 * p4 + 4 * h + 2 * e;
        unsigned pk = pkbf(oacc[ca][r] * rl, oacc[ca][r + 1] * rl);
        *(unsigned*)&smem[tloc * 64 + swz(tloc, c >> 3) * 8 + (c & 7)] = pk;
      }
  __syncthreads();
#pragma unroll
  for (int u = 0; u < 4; ++u) {
    int unit = u * 256 + TID;
    int row = unit >> 3, ch = unit & 7;
    u16x8 v = *(const u16x8*)&smem[row * 64 + swz(row, ch) * 8];
    *(u16x8*)&aT[((size_t)b * 1024 + t0 + row) * 512 + hd * 64 + ch * 8] = v;
  }
}

extern "C" void kernel_launch(void* const* d_in, const int* in_sizes, int n_in,
                              void* d_out, int out_size, void* d_ws, size_t ws_size,
                              hipStream_t stream) {
  const float* x = (const float*)d_in[0];
  const float* gamma = (const float*)d_in[1];
  const float* beta = (const float*)d_in[2];
  const float* w_qkv = (const float*)d_in[3];
  const float* b_qkv = (const float*)d_in[4];
  const float* w_proj = (const float*)d_in[5];
  const float* b_proj = (const float*)d_in[6];
  float* out = (float*)d_out;

  u16* qT = (u16*)d_ws;                    // 64bh*1024*64 = 4194304 u16 (8MB)
  u16* kT = qT + 4194304;                  // 8MB
  u16* vbuf = kT + 4194304;                // 8MB
  u16* aTb = vbuf + 4194304;               // 8MB
  u16* wqb = aTb + 4194304;                // 1.5MB
  u16* wpb = wqb + 786432;                 // 0.5MB
  float* stats = (float*)(wpb + 262144);   // 512 floats
  u16* xnT = (u16*)d_out;                  // 8MB scratch in d_out (overwritten by proj)

  prep_w<<<dim3(1024), dim3(256), 0, stream>>>(w_qkv, w_proj, wqb, wpb);
  gn_stats<<<dim3(256), dim3(256), 0, stream>>>(x, stats);
  gn_apply<<<dim3(32, 8), dim3(256), 0, stream>>>(x, gamma, beta, stats, xnT);

  // Q,K rows (o<1024): transposed GEMM -> qT/kT
  mfma_gemm<0><<<dim3(8, 8, 8), dim3(256), 0, stream>>>(
      wqb, xnT, b_qkv, nullptr, qT, kT, nullptr);
  // V rows: normal GEMM -> vbuf[bh][c][s]
  mfma_gemm<1><<<dim3(4, 8, 8), dim3(256), 0, stream>>>(
      wqb + (size_t)1024 * 512, xnT, b_qkv + 1024, nullptr, vbuf, nullptr, nullptr);

  attn_mfma<<<dim3(8, 64), dim3(256), 0, stream>>>(qT, kT, vbuf, aTb);

  mfma_gemm<2><<<dim3(4, 8, 8), dim3(256), 0, stream>>>(
      wpb, aTb, b_proj, x, nullptr, nullptr, out);
}

// Round 5
// 126.146 us; speedup vs baseline: 4.2986x; 1.0876x over previous
//
#include <hip/hip_runtime.h>

typedef unsigned short u16;
using bf16x8 = __attribute__((ext_vector_type(8))) __bf16;
using f32x4  = __attribute__((ext_vector_type(4))) float;
using f32x16 = __attribute__((ext_vector_type(16))) float;
using u16x8  = __attribute__((ext_vector_type(8))) u16;

constexpr float QSC = 0.180336880111112f;  // 0.125 * log2(e): softmax in exp2 domain

#define TID ((int)threadIdx.x)

__device__ __forceinline__ float fexp2(float x) { return exp2f(x); }
__device__ __forceinline__ u16 f2bf(float f) {
  __bf16 h = (__bf16)f;
  return __builtin_bit_cast(u16, h);
}
__device__ __forceinline__ unsigned pkbf(float a, float b) {
  return (unsigned)f2bf(a) | ((unsigned)f2bf(b) << 16);
}
__device__ __forceinline__ bf16x8 ldfrag(const u16* p) {
  return __builtin_bit_cast(bf16x8, *(const u16x8*)p);
}
// XOR swizzle of 16B chunks within a 128B row
__device__ __forceinline__ int swz(int row, int ch) {
  return ch ^ (row & 7) ^ ((row >> 3) & 7);
}
__device__ __forceinline__ f32x4 mfma16(bf16x8 a, bf16x8 b, f32x4 c) {
  return __builtin_amdgcn_mfma_f32_16x16x32_bf16(a, b, c, 0, 0, 0);
}
__device__ __forceinline__ f32x16 mfma32(bf16x8 a, bf16x8 b, f32x16 c) {
  return __builtin_amdgcn_mfma_f32_32x32x16_bf16(a, b, c, 0, 0, 0);
}

// ---------------- GroupNorm pass 1 ----------------
__global__ __launch_bounds__(256) void gn_stats(const float* __restrict__ x,
                                                float* __restrict__ stats) {
  size_t base = ((size_t)blockIdx.x) << 14;
  const float4* xp = (const float4*)(x + base);
  float s = 0.f, ss = 0.f;
#pragma unroll
  for (int i = 0; i < 16; ++i) {
    float4 v = xp[TID + i * 256];
    s += v.x + v.y + v.z + v.w;
    ss += v.x * v.x + v.y * v.y + v.z * v.z + v.w * v.w;
  }
#pragma unroll
  for (int off = 32; off; off >>= 1) {
    s += __shfl_down(s, off);
    ss += __shfl_down(ss, off);
  }
  __shared__ float sm[4], ssm[4];
  if ((TID & 63) == 0) { sm[TID >> 6] = s; ssm[TID >> 6] = ss; }
  __syncthreads();
  if (TID == 0) {
    float tot = sm[0] + sm[1] + sm[2] + sm[3];
    float tots = ssm[0] + ssm[1] + ssm[2] + ssm[3];
    float mean = tot * (1.f / 16384.f);
    float var = tots * (1.f / 16384.f) - mean * mean;
    stats[blockIdx.x * 2] = mean;
    stats[blockIdx.x * 2 + 1] = rsqrtf(var + 1e-5f);
  }
}

// ---------------- GroupNorm pass 2: -> xnT[b][l][c] bf16 ----------------
__global__ __launch_bounds__(256) void gn_apply(
    const float* __restrict__ x, const float* __restrict__ gamma,
    const float* __restrict__ beta, const float* __restrict__ stats,
    u16* __restrict__ xnT) {
  __shared__ u16 xt[32 * 520];
  int l0 = blockIdx.x * 32, b = blockIdx.y;
  int li = TID & 31, cb = TID >> 5;
#pragma unroll 4
  for (int it = 0; it < 64; ++it) {
    int c = it * 8 + cb;
    int g = c >> 4;
    float mean = stats[(b * 32 + g) * 2];
    float rstd = stats[(b * 32 + g) * 2 + 1];
    float ga = gamma[c] * rstd;
    float be = beta[c] - mean * ga;
    float v = x[((size_t)b * 512 + c) * 1024 + l0 + li];
    xt[li * 520 + c] = f2bf(v * ga + be);
  }
  __syncthreads();
  int li2 = TID >> 3, u0 = TID & 7;
#pragma unroll
  for (int it = 0; it < 8; ++it) {
    int unit = u0 + it * 8;
    u16x8 v = *(const u16x8*)&xt[li2 * 520 + unit * 8];
    *(u16x8*)&xnT[((size_t)b * 1024 + l0 + li2) * 512 + unit * 8] = v;
  }
}

// ---------------- weight fp32 -> bf16 ----------------
__global__ __launch_bounds__(256) void prep_w(const float* __restrict__ wq,
                                              const float* __restrict__ wp,
                                              u16* __restrict__ wqb,
                                              u16* __restrict__ wpb) {
  int i = blockIdx.x * 256 + TID;
  if (i < 196608) {
    float4 v = ((const float4*)wq)[i];
    u16* o = wqb + i * 4;
    o[0] = f2bf(v.x); o[1] = f2bf(v.y); o[2] = f2bf(v.z); o[3] = f2bf(v.w);
  } else {
    int j = i - 196608;
    float4 v = ((const float4*)wp)[j];
    u16* o = wpb + j * 4;
    o[0] = f2bf(v.x); o[1] = f2bf(v.y); o[2] = f2bf(v.z); o[3] = f2bf(v.w);
  }
}

// ---------------- bf16 MFMA GEMM over k=512 ----------------
// A [.][512] bf16, Bt [b][1024][512] bf16 (k-contiguous).
// MODE 0 (QK, transposed output): D[l][o]; Q (o<512, scaled QSC) -> qT[bh][t][c],
//          K -> kT[bh][s][c].  Coalesced via LDS repack epilogue.
// MODE 1 (V): D[o][l] -> vb[bh][c][s] bf16.  Coalesced via LDS repack epilogue.
// MODE 2 (proj): normal, fp32 out + bias + resid.
template <int MODE>
__global__ __launch_bounds__(256) void mfma_gemm(
    const u16* __restrict__ A, const u16* __restrict__ Bt,
    const float* __restrict__ bias, const float* __restrict__ resid,
    u16* __restrict__ o16a, u16* __restrict__ o16b, float* __restrict__ of) {
  __shared__ u16 Al[128 * 64], Bl[128 * 64];
  int m0 = blockIdx.x * 128, n0 = blockIdx.y * 128, b = blockIdx.z;
  int lane = TID & 63, w = TID >> 6;
  int mw = (w >> 1) * 64, nw = (w & 1) * 64;
  const u16* Bb = Bt + ((size_t)b) * 1024 * 512;
  f32x4 acc[4][4] = {};
  for (int k0 = 0; k0 < 512; k0 += 64) {
#pragma unroll
    for (int u = 0; u < 4; ++u) {
      int unit = u * 256 + TID;
      int row = unit >> 3, ch = unit & 7;
      u16x8 av = *(const u16x8*)&A[(size_t)(m0 + row) * 512 + k0 + ch * 8];
      u16x8 bv = *(const u16x8*)&Bb[(size_t)(n0 + row) * 512 + k0 + ch * 8];
      *(u16x8*)&Al[row * 64 + swz(row, ch) * 8] = av;
      *(u16x8*)&Bl[row * 64 + swz(row, ch) * 8] = bv;
    }
    __syncthreads();
    bf16x8 xf[4][2];
#pragma unroll
    for (int xi = 0; xi < 4; ++xi)
#pragma unroll
      for (int kf = 0; kf < 2; ++kf) {
        int row = (MODE == 0 ? nw : mw) + xi * 16 + (lane & 15);
        int lc = kf * 4 + (lane >> 4);
        const u16* Xl = (MODE == 0) ? Bl : Al;
        xf[xi][kf] = ldfrag(&Xl[row * 64 + swz(row, lc) * 8]);
      }
#pragma unroll
    for (int yi = 0; yi < 4; ++yi) {
      int row = (MODE == 0 ? mw : nw) + yi * 16 + (lane & 15);
      int lc = lane >> 4;
      const u16* Yl = (MODE == 0) ? Al : Bl;
      bf16x8 y0 = ldfrag(&Yl[row * 64 + swz(row, lc) * 8]);
      bf16x8 y1 = ldfrag(&Yl[row * 64 + swz(row, lc + 4) * 8]);
#pragma unroll
      for (int xi = 0; xi < 4; ++xi) {
        acc[xi][yi] = mfma16(xf[xi][0], y0, acc[xi][yi]);
        acc[xi][yi] = mfma16(xf[xi][1], y1, acc[xi][yi]);
      }
    }
    __syncthreads();
  }
  if constexpr (MODE == 0) {
    // acc[xi][yi][r]: l = n0+nw+xi*16+(lane>>4)*4+r, o = m0+mw+yi*16+(lane&15)
    u16* dst = (m0 < 512) ? o16a : o16b;
    bool isq = (m0 < 512);
    u16* RP = Al;  // repack: [l 128][oc 64] u16, swizzled
    for (int ho = 0; ho < 2; ++ho) {
      if ((w >> 1) == ho) {
#pragma unroll
        for (int xi = 0; xi < 4; ++xi)
#pragma unroll
          for (int yi = 0; yi < 4; ++yi)
#pragma unroll
            for (int r = 0; r < 4; ++r) {
              int lloc = nw + xi * 16 + (lane >> 4) * 4 + r;
              int oc = yi * 16 + (lane & 15);
              float v = acc[xi][yi][r] + bias[m0 + ho * 64 + oc];
              if (isq) v *= QSC;
              RP[lloc * 64 + swz(lloc, oc >> 3) * 8 + (oc & 7)] = f2bf(v);
            }
      }
      __syncthreads();
      int hd = ((m0 >> 6) + ho) & 7;
#pragma unroll
      for (int uu = 0; uu < 4; ++uu) {
        int unit = uu * 256 + TID;
        int row = unit >> 3, ch = unit & 7;
        u16x8 v = *(const u16x8*)&RP[row * 64 + swz(row, ch) * 8];
        *(u16x8*)&dst[((size_t)(b * 8 + hd) * 1024 + n0 + row) * 64 + ch * 8] = v;
      }
      __syncthreads();
    }
  } else if constexpr (MODE == 1) {
    // acc[xi][yi][r]: o = m0+mw+xi*16+(lane>>4)*4+r, l = n0+nw+yi*16+(lane&15)
    u16* RP = Al;  // repack: [o 64][l 128] u16, swizzled (16 chunks/row)
    for (int ho = 0; ho < 2; ++ho) {
      if ((w >> 1) == ho) {
#pragma unroll
        for (int xi = 0; xi < 4; ++xi)
#pragma unroll
          for (int yi = 0; yi < 4; ++yi)
#pragma unroll
            for (int r = 0; r < 4; ++r) {
              int oloc = xi * 16 + (lane >> 4) * 4 + r;
              int lloc = nw + yi * 16 + (lane & 15);
              float v = acc[xi][yi][r] + bias[m0 + ho * 64 + oloc];
              RP[oloc * 128 + swz(oloc, lloc >> 3) * 8 + (lloc & 7)] = f2bf(v);
            }
      }
      __syncthreads();
#pragma unroll
      for (int uu = 0; uu < 4; ++uu) {
        int unit = uu * 256 + TID;
        int ro = unit >> 4, ch = unit & 15;
        u16x8 v = *(const u16x8*)&RP[ro * 128 + swz(ro, ch) * 8];
        *(u16x8*)&o16a[((size_t)(b * 8 + (m0 >> 6) + ho) * 64 + ro) * 1024 + n0 +
                       ch * 8] = v;
      }
      __syncthreads();
    }
  } else {
#pragma unroll
    for (int xi = 0; xi < 4; ++xi)
#pragma unroll
      for (int yi = 0; yi < 4; ++yi)
#pragma unroll
        for (int r = 0; r < 4; ++r) {
          int o = m0 + mw + xi * 16 + (lane >> 4) * 4 + r;
          int l = n0 + nw + yi * 16 + (lane & 15);
          size_t idx = ((size_t)b * 512 + o) * 1024 + l;
          of[idx] = acc[xi][yi][r] + bias[o] + resid[idx];
        }
  }
}

// ---------------- MFMA flash attention, 32x32, swapped operands ----------------
// Block: 128 queries x (b,h); 4 waves x 32 q-rows. Lane owns q-row t = lane&31.
// Async-staged K/V (global->reg early, reg->LDS next iter), defer-max softmax.
__global__ __launch_bounds__(256) void attn_mfma(const u16* __restrict__ qT,
                                                 const u16* __restrict__ kT,
                                                 const u16* __restrict__ vb,
                                                 u16* __restrict__ aT) {
  __shared__ u16 smem[8192];  // Ks[64][64] | Vs[64][64]; reused as Ot[128][64]
  u16* Ks = smem;
  u16* Vs = smem + 4096;
  int t0 = blockIdx.x * 128;
  int bh = blockIdx.y, b = bh >> 3, hd = bh & 7;
  int lane = TID & 63, w = TID >> 6;
  int h = lane >> 5, ln = lane & 31;
  int t = t0 + w * 32 + ln;
  const u16* qp = qT + ((size_t)bh * 1024 + t) * 64;
  const u16* kbase = kT + (size_t)bh * 1024 * 64;
  const u16* vbase = vb + (size_t)bh * 64 * 1024;
  bf16x8 qf[4];
#pragma unroll
  for (int kc = 0; kc < 4; ++kc) qf[kc] = ldfrag(qp + kc * 16 + h * 8);
  float m_r = -1e30f, l_r = 0.f;
  f32x16 oacc[2] = {};

  // staging unit geometry: unit = u*256+TID -> row=unit>>3 (0..63), ch=unit&7
  int row0 = TID >> 3, ch0 = TID & 7;
  int row1 = (256 + TID) >> 3, ch1 = TID & 7;
  u16x8 kr0, kr1, vr0, vr1;
  kr0 = *(const u16x8*)&kbase[(size_t)row0 * 64 + ch0 * 8];
  kr1 = *(const u16x8*)&kbase[(size_t)row1 * 64 + ch1 * 8];
  vr0 = *(const u16x8*)&vbase[(size_t)row0 * 1024 + ch0 * 8];
  vr1 = *(const u16x8*)&vbase[(size_t)row1 * 1024 + ch1 * 8];

  for (int tile = 0; tile < 16; ++tile) {
    // write staged regs -> LDS
    *(u16x8*)&Ks[row0 * 64 + swz(row0, ch0) * 8] = kr0;
    *(u16x8*)&Ks[row1 * 64 + swz(row1, ch1) * 8] = kr1;
    *(u16x8*)&Vs[row0 * 64 + swz(row0, ch0) * 8] = vr0;
    *(u16x8*)&Vs[row1 * 64 + swz(row1, ch1) * 8] = vr1;
    __syncthreads();
    // issue next tile's global loads (land during this tile's compute)
    if (tile < 15) {
      int sn = (tile + 1) * 64;
      kr0 = *(const u16x8*)&kbase[(size_t)(sn + row0) * 64 + ch0 * 8];
      kr1 = *(const u16x8*)&kbase[(size_t)(sn + row1) * 64 + ch1 * 8];
      vr0 = *(const u16x8*)&vbase[(size_t)row0 * 1024 + sn + ch0 * 8];
      vr1 = *(const u16x8*)&vbase[(size_t)row1 * 1024 + sn + ch1 * 8];
    }
    // S^T[s][t] = sum_c K[s][c] * Q[t][c]  (log2 units; Q pre-scaled by QSC)
    f32x16 sacc[2] = {};
    __builtin_amdgcn_s_setprio(1);
#pragma unroll
    for (int sb = 0; sb < 2; ++sb) {
      int srow = sb * 32 + ln;
#pragma unroll
      for (int kc = 0; kc < 4; ++kc) {
        bf16x8 kf = ldfrag(&Ks[srow * 64 + swz(srow, kc * 2 + h) * 8]);
        sacc[sb] = mfma32(kf, qf[kc], sacc[sb]);
      }
    }
    __builtin_amdgcn_s_setprio(0);
    // online softmax; lane owns row t, 32 of 64 s-values (partner = lane^32)
    float mp[4];
#pragma unroll
    for (int q = 0; q < 4; ++q) {
      mp[q] = fmaxf(fmaxf(sacc[0][q * 4], sacc[0][q * 4 + 1]),
                    fmaxf(sacc[0][q * 4 + 2], sacc[0][q * 4 + 3]));
      mp[q] = fmaxf(mp[q], fmaxf(fmaxf(sacc[1][q * 4], sacc[1][q * 4 + 1]),
                                 fmaxf(sacc[1][q * 4 + 2], sacc[1][q * 4 + 3])));
    }
    float mx = fmaxf(fmaxf(mp[0], mp[1]), fmaxf(mp[2], mp[3]));
    mx = fmaxf(mx, __shfl_xor(mx, 32));
    // defer-max: skip rescale when growth bounded (P <= 2^8, safe in f32/bf16)
    bool noresc = (__all(mx <= m_r + 8.f) != 0);
    if (!noresc) {
      float mn = fmaxf(m_r, mx);
      float al = fexp2(m_r - mn);
      m_r = mn;
      l_r *= al;
#pragma unroll
      for (int ca = 0; ca < 2; ++ca)
#pragma unroll
        for (int i = 0; i < 16; ++i) oacc[ca][i] *= al;
    }
    float rp[4] = {0.f, 0.f, 0.f, 0.f};
#pragma unroll
    for (int sb = 0; sb < 2; ++sb)
#pragma unroll
      for (int i = 0; i < 16; ++i) {
        float pv = fexp2(sacc[sb][i] - m_r);
        sacc[sb][i] = pv;
        rp[i & 3] += pv;
      }
    float rs = (rp[0] + rp[1]) + (rp[2] + rp[3]);
    rs += __shfl_xor(rs, 32);
    l_r += rs;
    // pack P pairs: W[sb][p4][e] = bf16x2 of s = sb*32 + 8*p4 + 4*h + 2*e (+1)
    unsigned W[2][4][2];
#pragma unroll
    for (int sb = 0; sb < 2; ++sb)
#pragma unroll
      for (int p4 = 0; p4 < 4; ++p4)
#pragma unroll
        for (int e = 0; e < 2; ++e)
          W[sb][p4][e] = pkbf(sacc[sb][p4 * 4 + 2 * e], sacc[sb][p4 * 4 + 2 * e + 1]);
    // per 16-k step m: exchange with lane^32, assemble B-frag, PV
#pragma unroll
    for (int m = 0; m < 4; ++m) {
      int sb = m >> 1, q = (m & 1) * 2;
      unsigned a0 = W[sb][q][0], a1 = W[sb][q][1];
      unsigned b0 = W[sb][q + 1][0], b1 = W[sb][q + 1][1];
      unsigned s0w = h ? a0 : b0;
      unsigned s1w = h ? a1 : b1;
      unsigned r0 = (unsigned)__shfl_xor((int)s0w, 32);
      unsigned r1 = (unsigned)__shfl_xor((int)s1w, 32);
      unsigned w0 = h ? r0 : a0;
      unsigned w1 = h ? r1 : a1;
      unsigned w2 = h ? b0 : r0;
      unsigned w3 = h ? b1 : r1;
      uint4 pw = make_uint4(w0, w1, w2, w3);
      bf16x8 pf = __builtin_bit_cast(bf16x8, pw);
      __builtin_amdgcn_s_setprio(1);
#pragma unroll
      for (int ca = 0; ca < 2; ++ca) {
        int crow = ca * 32 + ln;
        bf16x8 vf = ldfrag(&Vs[crow * 64 + swz(crow, m * 2 + h) * 8]);
        oacc[ca] = mfma32(vf, pf, oacc[ca]);  // O^T[c][t]
      }
      __builtin_amdgcn_s_setprio(0);
    }
    __syncthreads();
  }
  // O^T -> LDS [t][c] (swizzled) -> coalesced aT[b][t][hd*64+c]
  float rl = 1.f / l_r;
  int tloc = w * 32 + ln;
#pragma unroll
  for (int ca = 0; ca < 2; ++ca)
#pragma unroll
    for (int p4 = 0; p4 < 4; ++p4)
#pragma unroll
      for (int e = 0; e < 2; ++e) {
        int r = p4 * 4 + e * 2;
        int c = ca * 32 + 8 * p4 + 4 * h + 2 * e;
        unsigned pk = pkbf(oacc[ca][r] * rl, oacc[ca][r + 1] * rl);
        *(unsigned*)&smem[tloc * 64 + swz(tloc, c >> 3) * 8 + (c & 7)] = pk;
      }
  __syncthreads();
#pragma unroll
  for (int u = 0; u < 4; ++u) {
    int unit = u * 256 + TID;
    int row = unit >> 3, ch = unit & 7;
    u16x8 v = *(const u16x8*)&smem[row * 64 + swz(row, ch) * 8];
    *(u16x8*)&aT[((size_t)b * 1024 + t0 + row) * 512 + hd * 64 + ch * 8] = v;
  }
}

extern "C" void kernel_launch(void* const* d_in, const int* in_sizes, int n_in,
                              void* d_out, int out_size, void* d_ws, size_t ws_size,
                              hipStream_t stream) {
  const float* x = (const float*)d_in[0];
  const float* gamma = (const float*)d_in[1];
  const float* beta = (const float*)d_in[2];
  const float* w_qkv = (const float*)d_in[3];
  const float* b_qkv = (const float*)d_in[4];
  const float* w_proj = (const float*)d_in[5];
  const float* b_proj = (const float*)d_in[6];
  float* out = (float*)d_out;

  u16* qT = (u16*)d_ws;                    // 64bh*1024*64 = 4194304 u16 (8MB)
  u16* kT = qT + 4194304;                  // 8MB
  u16* vbuf = kT + 4194304;                // 8MB
  u16* aTb = vbuf + 4194304;               // 8MB
  u16* wqb = aTb + 4194304;                // 1.5MB
  u16* wpb = wqb + 786432;                 // 0.5MB
  float* stats = (float*)(wpb + 262144);   // 512 floats
  u16* xnT = (u16*)d_out;                  // 8MB scratch in d_out (overwritten by proj)

  prep_w<<<dim3(1024), dim3(256), 0, stream>>>(w_qkv, w_proj, wqb, wpb);
  gn_stats<<<dim3(256), dim3(256), 0, stream>>>(x, stats);
  gn_apply<<<dim3(32, 8), dim3(256), 0, stream>>>(x, gamma, beta, stats, xnT);

  // Q,K rows (o<1024): transposed GEMM -> qT/kT
  mfma_gemm<0><<<dim3(8, 8, 8), dim3(256), 0, stream>>>(
      wqb, xnT, b_qkv, nullptr, qT, kT, nullptr);
  // V rows: normal GEMM -> vbuf[bh][c][s]
  mfma_gemm<1><<<dim3(4, 8, 8), dim3(256), 0, stream>>>(
      wqb + (size_t)1024 * 512, xnT, b_qkv + 1024, nullptr, vbuf, nullptr, nullptr);

  attn_mfma<<<dim3(8, 64), dim3(256), 0, stream>>>(qT, kT, vbuf, aTb);

  mfma_gemm<2><<<dim3(4, 8, 8), dim3(256), 0, stream>>>(
      wpb, aTb, b_proj, x, nullptr, nullptr, out);
}

// Round 6
// 100.914 us; speedup vs baseline: 5.3734x; 1.2500x over previous
//
#include <hip/hip_runtime.h>

typedef unsigned short u16;
using bf16x8 = __attribute__((ext_vector_type(8))) __bf16;
using f32x4  = __attribute__((ext_vector_type(4))) float;
using f32x16 = __attribute__((ext_vector_type(16))) float;
using u16x8  = __attribute__((ext_vector_type(8))) u16;

constexpr float QSC = 0.180336880111112f;  // 0.125 * log2(e): softmax in exp2 domain

#define TID ((int)threadIdx.x)

__device__ __forceinline__ float fexp2(float x) { return exp2f(x); }
__device__ __forceinline__ u16 f2bf(float f) {
  __bf16 h = (__bf16)f;
  return __builtin_bit_cast(u16, h);
}
__device__ __forceinline__ unsigned pkbf(float a, float b) {
  return (unsigned)f2bf(a) | ((unsigned)f2bf(b) << 16);
}
__device__ __forceinline__ bf16x8 ldfrag(const u16* p) {
  return __builtin_bit_cast(bf16x8, *(const u16x8*)p);
}
// XOR swizzle of 16B chunks within a 128B row (involution per row)
__device__ __forceinline__ int swz(int row, int ch) {
  return ch ^ (row & 7) ^ ((row >> 3) & 7);
}
// async global->LDS, 16B per lane; LDS dest linear (wave-uniform base + lane*16)
__device__ __forceinline__ void gload16(const u16* g, u16* l) {
  __builtin_amdgcn_global_load_lds(
      (__attribute__((address_space(1))) void*)g,
      (__attribute__((address_space(3))) void*)l, 16, 0, 0);
}
__device__ __forceinline__ f32x4 mfma16(bf16x8 a, bf16x8 b, f32x4 c) {
  return __builtin_amdgcn_mfma_f32_16x16x32_bf16(a, b, c, 0, 0, 0);
}
__device__ __forceinline__ f32x16 mfma32(bf16x8 a, bf16x8 b, f32x16 c) {
  return __builtin_amdgcn_mfma_f32_32x32x16_bf16(a, b, c, 0, 0, 0);
}

// ---------------- fused: weight fp32->bf16 (blocks 0..1023) + GN stats (1024..1279) ----
__global__ __launch_bounds__(256) void prep_stats(
    const float* __restrict__ wq, const float* __restrict__ wp,
    u16* __restrict__ wqb, u16* __restrict__ wpb,
    const float* __restrict__ x, float* __restrict__ stats) {
  __shared__ float sm[4], ssm[4];
  int bid = blockIdx.x;
  if (bid < 1024) {
    int i = bid * 256 + TID;
    if (i < 196608) {
      float4 v = ((const float4*)wq)[i];
      u16* o = wqb + i * 4;
      o[0] = f2bf(v.x); o[1] = f2bf(v.y); o[2] = f2bf(v.z); o[3] = f2bf(v.w);
    } else {
      int j = i - 196608;
      float4 v = ((const float4*)wp)[j];
      u16* o = wpb + j * 4;
      o[0] = f2bf(v.x); o[1] = f2bf(v.y); o[2] = f2bf(v.z); o[3] = f2bf(v.w);
    }
    return;
  }
  int blk = bid - 1024;
  size_t base = ((size_t)blk) << 14;
  const float4* xp = (const float4*)(x + base);
  float s = 0.f, ss = 0.f;
#pragma unroll
  for (int i = 0; i < 16; ++i) {
    float4 v = xp[TID + i * 256];
    s += v.x + v.y + v.z + v.w;
    ss += v.x * v.x + v.y * v.y + v.z * v.z + v.w * v.w;
  }
#pragma unroll
  for (int off = 32; off; off >>= 1) {
    s += __shfl_down(s, off);
    ss += __shfl_down(ss, off);
  }
  if ((TID & 63) == 0) { sm[TID >> 6] = s; ssm[TID >> 6] = ss; }
  __syncthreads();
  if (TID == 0) {
    float tot = sm[0] + sm[1] + sm[2] + sm[3];
    float tots = ssm[0] + ssm[1] + ssm[2] + ssm[3];
    float mean = tot * (1.f / 16384.f);
    float var = tots * (1.f / 16384.f) - mean * mean;
    stats[blk * 2] = mean;
    stats[blk * 2 + 1] = rsqrtf(var + 1e-5f);
  }
}

// ---------------- GroupNorm apply: -> xnT[b][l][c] bf16 ----------------
__global__ __launch_bounds__(256) void gn_apply(
    const float* __restrict__ x, const float* __restrict__ gamma,
    const float* __restrict__ beta, const float* __restrict__ stats,
    u16* __restrict__ xnT) {
  __shared__ u16 xt[32 * 520];
  int l0 = blockIdx.x * 32, b = blockIdx.y;
  int li = TID & 31, cb = TID >> 5;
#pragma unroll 4
  for (int it = 0; it < 64; ++it) {
    int c = it * 8 + cb;
    int g = c >> 4;
    float mean = stats[(b * 32 + g) * 2];
    float rstd = stats[(b * 32 + g) * 2 + 1];
    float ga = gamma[c] * rstd;
    float be = beta[c] - mean * ga;
    float v = x[((size_t)b * 512 + c) * 1024 + l0 + li];
    xt[li * 520 + c] = f2bf(v * ga + be);
  }
  __syncthreads();
  int li2 = TID >> 3, u0 = TID & 7;
#pragma unroll
  for (int it = 0; it < 8; ++it) {
    int unit = u0 + it * 8;
    u16x8 v = *(const u16x8*)&xt[li2 * 520 + unit * 8];
    *(u16x8*)&xnT[((size_t)b * 1024 + l0 + li2) * 512 + unit * 8] = v;
  }
}

// ---------------- unified QKV GEMM (transposed product D[l][o]) ----------------
// A=wqb [1536][512] bf16, Bt=xnT [b][1024][512] bf16.
// m0<512: Q (scaled QSC) -> qT[bh][t][c]; m0<1024: K -> kT[bh][s][c];
// else: V -> vbuf[bh][c][s].  All via LDS repack, coalesced u16x8 stores.
__global__ __launch_bounds__(256) void qkv_gemm(
    const u16* __restrict__ A, const u16* __restrict__ Bt,
    const float* __restrict__ bias,
    u16* __restrict__ qT, u16* __restrict__ kT, u16* __restrict__ vbuf) {
  __shared__ u16 Al[8192], Bl[8192];
  int lin = blockIdx.x;            // 768 = 8 XCD chunks x 96 (12 m x 8 n)
  int b = lin & 7;                 // one batch per XCD
  int rem = lin >> 3;
  int mi = rem % 12, ni = rem / 12;
  int m0 = mi * 128, n0 = ni * 128;
  int lane = TID & 63, w = TID >> 6;
  int mw = (w >> 1) * 64, nw = (w & 1) * 64;
  const u16* Bb = Bt + (size_t)b * 1024 * 512;
  f32x4 acc[4][4] = {};
  for (int k0 = 0; k0 < 512; k0 += 64) {
#pragma unroll
    for (int u = 0; u < 4; ++u) {
      int unit = u * 256 + TID, row = unit >> 3, ch = unit & 7;
      gload16(&A[(size_t)(m0 + row) * 512 + k0 + swz(row, ch) * 8], &Al[unit * 8]);
      gload16(&Bb[(size_t)(n0 + row) * 512 + k0 + swz(row, ch) * 8], &Bl[unit * 8]);
    }
    __syncthreads();
    bf16x8 xf[4][2];
#pragma unroll
    for (int xi = 0; xi < 4; ++xi)
#pragma unroll
      for (int kf = 0; kf < 2; ++kf) {
        int row = nw + xi * 16 + (lane & 15);
        int lc = kf * 4 + (lane >> 4);
        xf[xi][kf] = ldfrag(&Bl[row * 64 + swz(row, lc) * 8]);
      }
#pragma unroll
    for (int yi = 0; yi < 4; ++yi) {
      int row = mw + yi * 16 + (lane & 15);
      int lc = lane >> 4;
      bf16x8 y0 = ldfrag(&Al[row * 64 + swz(row, lc) * 8]);
      bf16x8 y1 = ldfrag(&Al[row * 64 + swz(row, lc + 4) * 8]);
#pragma unroll
      for (int xi = 0; xi < 4; ++xi) {
        acc[xi][yi] = mfma16(xf[xi][0], y0, acc[xi][yi]);
        acc[xi][yi] = mfma16(xf[xi][1], y1, acc[xi][yi]);
      }
    }
    __syncthreads();
  }
  // acc[xi][yi][r]: l = n0+nw+xi*16+(lane>>4)*4+r,  o = m0+mw+yi*16+(lane&15)
  int sel = m0 >> 9;  // 0=Q 1=K 2=V
  if (sel < 2) {
    u16* dst = sel ? kT : qT;
    int mbase = m0 & 511;
    u16* RP = Al;  // [l 128][oc 64]
    for (int ho = 0; ho < 2; ++ho) {
      if ((w >> 1) == ho) {
#pragma unroll
        for (int xi = 0; xi < 4; ++xi)
#pragma unroll
          for (int yi = 0; yi < 4; ++yi)
#pragma unroll
            for (int r = 0; r < 4; ++r) {
              int lloc = nw + xi * 16 + (lane >> 4) * 4 + r;
              int oc = yi * 16 + (lane & 15);
              float v = acc[xi][yi][r] + bias[m0 + ho * 64 + oc];
              if (sel == 0) v *= QSC;
              RP[lloc * 64 + swz(lloc, oc >> 3) * 8 + (oc & 7)] = f2bf(v);
            }
      }
      __syncthreads();
      int head = (mbase >> 6) + ho;
#pragma unroll
      for (int uu = 0; uu < 4; ++uu) {
        int unit = uu * 256 + TID, row = unit >> 3, ch = unit & 7;
        u16x8 v = *(const u16x8*)&RP[row * 64 + swz(row, ch) * 8];
        *(u16x8*)&dst[((size_t)(b * 8 + head) * 1024 + n0 + row) * 64 + ch * 8] = v;
      }
      __syncthreads();
    }
  } else {
    int mbase = m0 - 1024;
    u16* RP = Al;  // [oc 64][l 128]
    for (int ho = 0; ho < 2; ++ho) {
      if ((w >> 1) == ho) {
#pragma unroll
        for (int xi = 0; xi < 4; ++xi)
#pragma unroll
          for (int yi = 0; yi < 4; ++yi)
#pragma unroll
            for (int r = 0; r < 4; ++r) {
              int lloc = nw + xi * 16 + (lane >> 4) * 4 + r;
              int oc = yi * 16 + (lane & 15);
              float v = acc[xi][yi][r] + bias[m0 + ho * 64 + oc];
              RP[oc * 128 + swz(oc, lloc >> 3) * 8 + (lloc & 7)] = f2bf(v);
            }
      }
      __syncthreads();
      int head = (mbase >> 6) + ho;
#pragma unroll
      for (int uu = 0; uu < 4; ++uu) {
        int unit = uu * 256 + TID, ro = unit >> 4, ch = unit & 15;
        u16x8 v = *(const u16x8*)&RP[ro * 128 + swz(ro, ch) * 8];
        *(u16x8*)&vbuf[((size_t)(b * 8 + head) * 64 + ro) * 1024 + n0 + ch * 8] = v;
      }
      __syncthreads();
    }
  }
}

// ---------------- MFMA flash attention, 32x32, swapped operands ----------------
// 1D grid 512, XCD-swizzled so each XCD owns 8 bh (K/V L2-resident).
// Double-buffered LDS, global_load_lds staging, ONE barrier per tile.
__global__ __launch_bounds__(256) void attn_mfma(const u16* __restrict__ qT,
                                                 const u16* __restrict__ kT,
                                                 const u16* __restrict__ vb,
                                                 u16* __restrict__ aT) {
  __shared__ u16 smem[16384];  // 2 x (Ks[64][64] | Vs[64][64]); repack reuses buf0
  int lin = blockIdx.x;
  int rem = lin >> 3;
  int bh = (lin & 7) * 8 + (rem >> 3);
  int t0 = (rem & 7) * 128;
  int b = bh >> 3, hd = bh & 7;
  int lane = TID & 63, w = TID >> 6;
  int h = lane >> 5, ln = lane & 31;
  int t = t0 + w * 32 + ln;
  const u16* qp = qT + ((size_t)bh * 1024 + t) * 64;
  const u16* kbase = kT + (size_t)bh * 1024 * 64;
  const u16* vbase = vb + (size_t)bh * 64 * 1024;
  bf16x8 qf[4];
#pragma unroll
  for (int kc = 0; kc < 4; ++kc) qf[kc] = ldfrag(qp + kc * 16 + h * 8);
  float m_r = -1e30f, l_r = 0.f;
  f32x16 oacc[2] = {};

  int u0 = TID, u1 = TID + 256;
  int r0 = u0 >> 3, c0 = u0 & 7;
  int r1 = u1 >> 3, c1 = u1 & 7;
  {  // stage tile 0 -> buf0
    u16* Ks = smem;
    u16* Vs = smem + 4096;
    gload16(&kbase[(size_t)r0 * 64 + swz(r0, c0) * 8], &Ks[u0 * 8]);
    gload16(&kbase[(size_t)r1 * 64 + swz(r1, c1) * 8], &Ks[u1 * 8]);
    gload16(&vbase[(size_t)r0 * 1024 + swz(r0, c0) * 8], &Vs[u0 * 8]);
    gload16(&vbase[(size_t)r1 * 1024 + swz(r1, c1) * 8], &Vs[u1 * 8]);
  }
  __syncthreads();
  for (int tile = 0; tile < 16; ++tile) {
    const u16* Ks = smem + (tile & 1) * 8192;
    const u16* Vs = Ks + 4096;
    if (tile < 15) {  // issue next tile into buf^1; lands by end-of-tile barrier
      int sn = (tile + 1) * 64;
      u16* Kn = smem + ((tile + 1) & 1) * 8192;
      u16* Vn = Kn + 4096;
      gload16(&kbase[(size_t)(sn + r0) * 64 + swz(r0, c0) * 8], &Kn[u0 * 8]);
      gload16(&kbase[(size_t)(sn + r1) * 64 + swz(r1, c1) * 8], &Kn[u1 * 8]);
      gload16(&vbase[(size_t)r0 * 1024 + sn + swz(r0, c0) * 8], &Vn[u0 * 8]);
      gload16(&vbase[(size_t)r1 * 1024 + sn + swz(r1, c1) * 8], &Vn[u1 * 8]);
    }
    // S^T[s][t] = sum_c K[s][c] * Q[t][c]  (log2 units; Q pre-scaled by QSC)
    f32x16 sacc[2] = {};
    __builtin_amdgcn_s_setprio(1);
#pragma unroll
    for (int sb = 0; sb < 2; ++sb) {
      int srow = sb * 32 + ln;
#pragma unroll
      for (int kc = 0; kc < 4; ++kc) {
        bf16x8 kf = ldfrag(&Ks[srow * 64 + swz(srow, kc * 2 + h) * 8]);
        sacc[sb] = mfma32(kf, qf[kc], sacc[sb]);
      }
    }
    __builtin_amdgcn_s_setprio(0);
    // online softmax; lane owns row t, 32 of 64 s-values (partner = lane^32)
    float mp[4];
#pragma unroll
    for (int q = 0; q < 4; ++q) {
      mp[q] = fmaxf(fmaxf(sacc[0][q * 4], sacc[0][q * 4 + 1]),
                    fmaxf(sacc[0][q * 4 + 2], sacc[0][q * 4 + 3]));
      mp[q] = fmaxf(mp[q], fmaxf(fmaxf(sacc[1][q * 4], sacc[1][q * 4 + 1]),
                                 fmaxf(sacc[1][q * 4 + 2], sacc[1][q * 4 + 3])));
    }
    float mx = fmaxf(fmaxf(mp[0], mp[1]), fmaxf(mp[2], mp[3]));
    mx = fmaxf(mx, __shfl_xor(mx, 32));
    // defer-max: skip rescale while growth bounded (P <= 2^8)
    bool noresc = (__all(mx <= m_r + 8.f) != 0);
    if (!noresc) {
      float mn = fmaxf(m_r, mx);
      float al = fexp2(m_r - mn);
      m_r = mn;
      l_r *= al;
#pragma unroll
      for (int ca = 0; ca < 2; ++ca)
#pragma unroll
        for (int i = 0; i < 16; ++i) oacc[ca][i] *= al;
    }
    float rp[4] = {0.f, 0.f, 0.f, 0.f};
#pragma unroll
    for (int sb = 0; sb < 2; ++sb)
#pragma unroll
      for (int i = 0; i < 16; ++i) {
        float pv = fexp2(sacc[sb][i] - m_r);
        sacc[sb][i] = pv;
        rp[i & 3] += pv;
      }
    float rs = (rp[0] + rp[1]) + (rp[2] + rp[3]);
    rs += __shfl_xor(rs, 32);
    l_r += rs;
    // pack P pairs: W[sb][p4][e] = bf16x2 of s = sb*32 + 8*p4 + 4*h + 2*e (+1)
    unsigned W[2][4][2];
#pragma unroll
    for (int sb = 0; sb < 2; ++sb)
#pragma unroll
      for (int p4 = 0; p4 < 4; ++p4)
#pragma unroll
        for (int e = 0; e < 2; ++e)
          W[sb][p4][e] = pkbf(sacc[sb][p4 * 4 + 2 * e], sacc[sb][p4 * 4 + 2 * e + 1]);
    // per 16-k step m: exchange with lane^32, assemble B-frag, PV
#pragma unroll
    for (int m = 0; m < 4; ++m) {
      int sb = m >> 1, q = (m & 1) * 2;
      unsigned a0 = W[sb][q][0], a1 = W[sb][q][1];
      unsigned b0 = W[sb][q + 1][0], b1 = W[sb][q + 1][1];
      unsigned s0w = h ? a0 : b0;
      unsigned s1w = h ? a1 : b1;
      unsigned x0 = (unsigned)__shfl_xor((int)s0w, 32);
      unsigned x1 = (unsigned)__shfl_xor((int)s1w, 32);
      unsigned w0 = h ? x0 : a0;
      unsigned w1 = h ? x1 : a1;
      unsigned w2 = h ? b0 : x0;
      unsigned w3 = h ? b1 : x1;
      uint4 pw = make_uint4(w0, w1, w2, w3);
      bf16x8 pf = __builtin_bit_cast(bf16x8, pw);
      __builtin_amdgcn_s_setprio(1);
#pragma unroll
      for (int ca = 0; ca < 2; ++ca) {
        int crow = ca * 32 + ln;
        bf16x8 vf = ldfrag(&Vs[crow * 64 + swz(crow, m * 2 + h) * 8]);
        oacc[ca] = mfma32(vf, pf, oacc[ca]);  // O^T[c][t]
      }
      __builtin_amdgcn_s_setprio(0);
    }
    __syncthreads();
  }
  // O^T -> LDS [t][c] (swizzled) -> coalesced aT[b][t][hd*64+c]
  float rl = 1.f / l_r;
  int tloc = w * 32 + ln;
#pragma unroll
  for (int ca = 0; ca < 2; ++ca)
#pragma unroll
    for (int p4 = 0; p4 < 4; ++p4)
#pragma unroll
      for (int e = 0; e < 2; ++e) {
        int r = p4 * 4 + e * 2;
        int c = ca * 32 + 8 * p4 + 4 * h + 2 * e;
        unsigned pk = pkbf(oacc[ca][r] * rl, oacc[ca][r + 1] * rl);
        *(unsigned*)&smem[tloc * 64 + swz(tloc, c >> 3) * 8 + (c & 7)] = pk;
      }
  __syncthreads();
#pragma unroll
  for (int u = 0; u < 4; ++u) {
    int unit = u * 256 + TID;
    int row = unit >> 3, ch = unit & 7;
    u16x8 v = *(const u16x8*)&smem[row * 64 + swz(row, ch) * 8];
    *(u16x8*)&aT[((size_t)b * 1024 + t0 + row) * 512 + hd * 64 + ch * 8] = v;
  }
}

// ---------------- proj GEMM: normal D[o][l], fp32 out + bias + resid ----------------
__global__ __launch_bounds__(256) void proj_gemm(
    const u16* __restrict__ A, const u16* __restrict__ Bt,
    const float* __restrict__ bias, const float* __restrict__ resid,
    float* __restrict__ of) {
  __shared__ u16 Al[8192], Bl[8192];
  int lin = blockIdx.x;           // 256 = 8 XCD chunks x 32 (4 m x 8 n)
  int b = lin & 7;
  int rem = lin >> 3;
  int mi = rem & 3, ni = rem >> 2;
  int m0 = mi * 128, n0 = ni * 128;
  int lane = TID & 63, w = TID >> 6;
  int mw = (w >> 1) * 64, nw = (w & 1) * 64;
  const u16* Bb = Bt + (size_t)b * 1024 * 512;
  f32x4 acc[4][4] = {};
  for (int k0 = 0; k0 < 512; k0 += 64) {
#pragma unroll
    for (int u = 0; u < 4; ++u) {
      int unit = u * 256 + TID, row = unit >> 3, ch = unit & 7;
      gload16(&A[(size_t)(m0 + row) * 512 + k0 + swz(row, ch) * 8], &Al[unit * 8]);
      gload16(&Bb[(size_t)(n0 + row) * 512 + k0 + swz(row, ch) * 8], &Bl[unit * 8]);
    }
    __syncthreads();
    bf16x8 xf[4][2];
#pragma unroll
    for (int xi = 0; xi < 4; ++xi)
#pragma unroll
      for (int kf = 0; kf < 2; ++kf) {
        int row = mw + xi * 16 + (lane & 15);
        int lc = kf * 4 + (lane >> 4);
        xf[xi][kf] = ldfrag(&Al[row * 64 + swz(row, lc) * 8]);
      }
#pragma unroll
    for (int yi = 0; yi < 4; ++yi) {
      int row = nw + yi * 16 + (lane & 15);
      int lc = lane >> 4;
      bf16x8 y0 = ldfrag(&Bl[row * 64 + swz(row, lc) * 8]);
      bf16x8 y1 = ldfrag(&Bl[row * 64 + swz(row, lc + 4) * 8]);
#pragma unroll
      for (int xi = 0; xi < 4; ++xi) {
        acc[xi][yi] = mfma16(xf[xi][0], y0, acc[xi][yi]);
        acc[xi][yi] = mfma16(xf[xi][1], y1, acc[xi][yi]);
      }
    }
    __syncthreads();
  }
#pragma unroll
  for (int xi = 0; xi < 4; ++xi)
#pragma unroll
    for (int yi = 0; yi < 4; ++yi)
#pragma unroll
      for (int r = 0; r < 4; ++r) {
        int o = m0 + mw + xi * 16 + (lane >> 4) * 4 + r;
        int l = n0 + nw + yi * 16 + (lane & 15);
        size_t idx = ((size_t)b * 512 + o) * 1024 + l;
        of[idx] = acc[xi][yi][r] + bias[o] + resid[idx];
      }
}

extern "C" void kernel_launch(void* const* d_in, const int* in_sizes, int n_in,
                              void* d_out, int out_size, void* d_ws, size_t ws_size,
                              hipStream_t stream) {
  const float* x = (const float*)d_in[0];
  const float* gamma = (const float*)d_in[1];
  const float* beta = (const float*)d_in[2];
  const float* w_qkv = (const float*)d_in[3];
  const float* b_qkv = (const float*)d_in[4];
  const float* w_proj = (const float*)d_in[5];
  const float* b_proj = (const float*)d_in[6];
  float* out = (float*)d_out;

  u16* qT = (u16*)d_ws;                    // 64bh*1024*64 = 4194304 u16 (8MB)
  u16* kT = qT + 4194304;                  // 8MB
  u16* vbuf = kT + 4194304;                // 8MB
  u16* aTb = vbuf + 4194304;               // 8MB
  u16* wqb = aTb + 4194304;                // 1.5MB
  u16* wpb = wqb + 786432;                 // 0.5MB
  float* stats = (float*)(wpb + 262144);   // 512 floats
  u16* xnT = (u16*)d_out;                  // 8MB scratch in d_out (overwritten by proj)

  prep_stats<<<dim3(1280), dim3(256), 0, stream>>>(w_qkv, w_proj, wqb, wpb, x, stats);
  gn_apply<<<dim3(32, 8), dim3(256), 0, stream>>>(x, gamma, beta, stats, xnT);
  qkv_gemm<<<dim3(768), dim3(256), 0, stream>>>(wqb, xnT, b_qkv, qT, kT, vbuf);
  attn_mfma<<<dim3(512), dim3(256), 0, stream>>>(qT, kT, vbuf, aTb);
  proj_gemm<<<dim3(256), dim3(256), 0, stream>>>(wpb, aTb, b_proj, x, out);
}

// Round 8
// 87.344 us; speedup vs baseline: 6.2082x; 1.1554x over previous
//
#include <hip/hip_runtime.h>

typedef unsigned short u16;
using bf16x8 = __attribute__((ext_vector_type(8))) __bf16;
using f32x4  = __attribute__((ext_vector_type(4))) float;
using f32x16 = __attribute__((ext_vector_type(16))) float;
using u16x8  = __attribute__((ext_vector_type(8))) u16;
using u32x2  = __attribute__((ext_vector_type(2))) unsigned;

constexpr float QSC = 0.180336880111112f;  // 0.125 * log2(e): softmax in exp2 domain

#define TID ((int)threadIdx.x)

__device__ __forceinline__ float fexp2(float x) {
#if __has_builtin(__builtin_amdgcn_exp2f)
  return __builtin_amdgcn_exp2f(x);
#else
  return exp2f(x);
#endif
}
__device__ __forceinline__ u16 f2bf(float f) {
  __bf16 h = (__bf16)f;
  return __builtin_bit_cast(u16, h);
}
// packed f32x2 -> bf16x2 (RNE), single instruction (T12 recipe; src0 -> lo16)
__device__ __forceinline__ unsigned cvtpk(float a, float b) {
  unsigned r;
  asm("v_cvt_pk_bf16_f32 %0, %1, %2" : "=v"(r) : "v"(a), "v"(b));
  return r;
}
// cross-half (lane i <-> lane i^32) reduce via permlane32_swap.
// NOTE: used ONLY where the result is invariant to the swap direction
// (max/add of own+partner values) — safe under either ISA reading.
__device__ __forceinline__ u32x2 plswap(unsigned d, unsigned s) {
#if __has_builtin(__builtin_amdgcn_permlane32_swap)
  return __builtin_amdgcn_permlane32_swap(d, s, false, false);
#else
  unsigned dx = (unsigned)__shfl_xor((int)d, 32);
  unsigned sx = (unsigned)__shfl_xor((int)s, 32);
  int hh = ((int)threadIdx.x >> 5) & 1;
  u32x2 r;
  r[0] = hh ? d : sx;
  r[1] = hh ? dx : s;
  return r;
#endif
}
__device__ __forceinline__ float xhalf_max(float x) {
  unsigned u = __builtin_bit_cast(unsigned, x);
  u32x2 r = plswap(u, u);
  return fmaxf(__builtin_bit_cast(float, r[0]), __builtin_bit_cast(float, r[1]));
}
__device__ __forceinline__ float xhalf_add(float x) {
  unsigned u = __builtin_bit_cast(unsigned, x);
  u32x2 r = plswap(u, u);
  return __builtin_bit_cast(float, r[0]) + __builtin_bit_cast(float, r[1]);
}
__device__ __forceinline__ bf16x8 ldfrag(const u16* p) {
  return __builtin_bit_cast(bf16x8, *(const u16x8*)p);
}
// XOR swizzle of 16B chunks within a 128B row (involution per row)
__device__ __forceinline__ int swz(int row, int ch) {
  return ch ^ (row & 7) ^ ((row >> 3) & 7);
}
// async global->LDS, 16B per lane; LDS dest linear (wave-uniform base + lane*16)
__device__ __forceinline__ void gload16(const u16* g, u16* l) {
  __builtin_amdgcn_global_load_lds(
      (__attribute__((address_space(1))) void*)g,
      (__attribute__((address_space(3))) void*)l, 16, 0, 0);
}
__device__ __forceinline__ f32x4 mfma16(bf16x8 a, bf16x8 b, f32x4 c) {
  return __builtin_amdgcn_mfma_f32_16x16x32_bf16(a, b, c, 0, 0, 0);
}
__device__ __forceinline__ f32x16 mfma32(bf16x8 a, bf16x8 b, f32x16 c) {
  return __builtin_amdgcn_mfma_f32_32x32x16_bf16(a, b, c, 0, 0, 0);
}

// ---------------- fused: weight fp32->bf16 (blocks 0..1023) + GN stats (1024..1279) ----
__global__ __launch_bounds__(256) void prep_stats(
    const float* __restrict__ wq, const float* __restrict__ wp,
    u16* __restrict__ wqb, u16* __restrict__ wpb,
    const float* __restrict__ x, float* __restrict__ stats) {
  __shared__ float sm[4], ssm[4];
  int bid = blockIdx.x;
  if (bid < 1024) {
    int i = bid * 256 + TID;
    if (i < 196608) {
      float4 v = ((const float4*)wq)[i];
      u16* o = wqb + i * 4;
      o[0] = f2bf(v.x); o[1] = f2bf(v.y); o[2] = f2bf(v.z); o[3] = f2bf(v.w);
    } else {
      int j = i - 196608;
      float4 v = ((const float4*)wp)[j];
      u16* o = wpb + j * 4;
      o[0] = f2bf(v.x); o[1] = f2bf(v.y); o[2] = f2bf(v.z); o[3] = f2bf(v.w);
    }
    return;
  }
  int blk = bid - 1024;
  size_t base = ((size_t)blk) << 14;
  const float4* xp = (const float4*)(x + base);
  float s = 0.f, ss = 0.f;
#pragma unroll
  for (int i = 0; i < 16; ++i) {
    float4 v = xp[TID + i * 256];
    s += v.x + v.y + v.z + v.w;
    ss += v.x * v.x + v.y * v.y + v.z * v.z + v.w * v.w;
  }
#pragma unroll
  for (int off = 32; off; off >>= 1) {
    s += __shfl_down(s, off);
    ss += __shfl_down(ss, off);
  }
  if ((TID & 63) == 0) { sm[TID >> 6] = s; ssm[TID >> 6] = ss; }
  __syncthreads();
  if (TID == 0) {
    float tot = sm[0] + sm[1] + sm[2] + sm[3];
    float tots = ssm[0] + ssm[1] + ssm[2] + ssm[3];
    float mean = tot * (1.f / 16384.f);
    float var = tots * (1.f / 16384.f) - mean * mean;
    stats[blk * 2] = mean;
    stats[blk * 2 + 1] = rsqrtf(var + 1e-5f);
  }
}

// ---------------- GroupNorm apply: -> xnT[b][l][c] bf16 ----------------
__global__ __launch_bounds__(256) void gn_apply(
    const float* __restrict__ x, const float* __restrict__ gamma,
    const float* __restrict__ beta, const float* __restrict__ stats,
    u16* __restrict__ xnT) {
  __shared__ u16 xt[32 * 520];
  int l0 = blockIdx.x * 32, b = blockIdx.y;
  int li = TID & 31, cb = TID >> 5;
#pragma unroll 4
  for (int it = 0; it < 64; ++it) {
    int c = it * 8 + cb;
    int g = c >> 4;
    float mean = stats[(b * 32 + g) * 2];
    float rstd = stats[(b * 32 + g) * 2 + 1];
    float ga = gamma[c] * rstd;
    float be = beta[c] - mean * ga;
    float v = x[((size_t)b * 512 + c) * 1024 + l0 + li];
    xt[li * 520 + c] = f2bf(v * ga + be);
  }
  __syncthreads();
  int li2 = TID >> 3, u0 = TID & 7;
#pragma unroll
  for (int it = 0; it < 8; ++it) {
    int unit = u0 + it * 8;
    u16x8 v = *(const u16x8*)&xt[li2 * 520 + unit * 8];
    *(u16x8*)&xnT[((size_t)b * 1024 + l0 + li2) * 512 + unit * 8] = v;
  }
}

// ---------------- unified QKV GEMM (transposed product D[l][o]) ----------------
// A=wqb [1536][512] bf16, Bt=xnT [b][1024][512] bf16.
// m0<512: Q (scaled QSC) -> qT[bh][t][c]; m0<1024: K -> kT[bh][s][c];
// else: V -> vbuf[bh][c][s].  Dual-LDS repack epilogue, 1 barrier, no idle waves.
__global__ __launch_bounds__(256) void qkv_gemm(
    const u16* __restrict__ A, const u16* __restrict__ Bt,
    const float* __restrict__ bias,
    u16* __restrict__ qT, u16* __restrict__ kT, u16* __restrict__ vbuf) {
  __shared__ u16 Al[8192], Bl[8192];
  int lin = blockIdx.x;            // 768 = 8 XCD chunks x 96 (12 m x 8 n)
  int b = lin & 7;                 // one batch per XCD
  int rem = lin >> 3;
  int mi = rem % 12, ni = rem / 12;
  int m0 = mi * 128, n0 = ni * 128;
  int lane = TID & 63, w = TID >> 6;
  int mw = (w >> 1) * 64, nw = (w & 1) * 64;
  const u16* Bb = Bt + (size_t)b * 1024 * 512;
  f32x4 acc[4][4] = {};
  for (int k0 = 0; k0 < 512; k0 += 64) {
#pragma unroll
    for (int u = 0; u < 4; ++u) {
      int unit = u * 256 + TID, row = unit >> 3, ch = unit & 7;
      gload16(&A[(size_t)(m0 + row) * 512 + k0 + swz(row, ch) * 8], &Al[unit * 8]);
      gload16(&Bb[(size_t)(n0 + row) * 512 + k0 + swz(row, ch) * 8], &Bl[unit * 8]);
    }
    __syncthreads();
    bf16x8 xf[4][2];
#pragma unroll
    for (int xi = 0; xi < 4; ++xi)
#pragma unroll
      for (int kf = 0; kf < 2; ++kf) {
        int row = nw + xi * 16 + (lane & 15);
        int lc = kf * 4 + (lane >> 4);
        xf[xi][kf] = ldfrag(&Bl[row * 64 + swz(row, lc) * 8]);
      }
#pragma unroll
    for (int yi = 0; yi < 4; ++yi) {
      int row = mw + yi * 16 + (lane & 15);
      int lc = lane >> 4;
      bf16x8 y0 = ldfrag(&Al[row * 64 + swz(row, lc) * 8]);
      bf16x8 y1 = ldfrag(&Al[row * 64 + swz(row, lc + 4) * 8]);
#pragma unroll
      for (int xi = 0; xi < 4; ++xi) {
        acc[xi][yi] = mfma16(xf[xi][0], y0, acc[xi][yi]);
        acc[xi][yi] = mfma16(xf[xi][1], y1, acc[xi][yi]);
      }
    }
    __syncthreads();
  }
  // acc[xi][yi][r]: l = nw+xi*16+(lane>>4)*4+r (local), o = m0+mw+yi*16+(lane&15)
  int sel = m0 >> 9;  // 0=Q 1=K 2=V
  int ho = w >> 1;    // which 64-wide output half this wave computed
  u16* RP = ho ? Bl : Al;
  if (sel < 2) {
    // RP[l 128][oc 64]
#pragma unroll
    for (int xi = 0; xi < 4; ++xi)
#pragma unroll
      for (int yi = 0; yi < 4; ++yi)
#pragma unroll
        for (int r = 0; r < 4; ++r) {
          int lloc = nw + xi * 16 + (lane >> 4) * 4 + r;
          int oc = yi * 16 + (lane & 15);
          float v = acc[xi][yi][r] + bias[m0 + ho * 64 + oc];
          if (sel == 0) v *= QSC;
          RP[lloc * 64 + swz(lloc, oc >> 3) * 8 + (oc & 7)] = f2bf(v);
        }
    __syncthreads();
    u16* dst = sel ? kT : qT;
    int h0 = (m0 & 511) >> 6;
#pragma unroll
    for (int uu = 0; uu < 4; ++uu) {
      int unit = uu * 256 + TID, row = unit >> 3, ch = unit & 7;
      u16x8 v0 = *(const u16x8*)&Al[row * 64 + swz(row, ch) * 8];
      u16x8 v1 = *(const u16x8*)&Bl[row * 64 + swz(row, ch) * 8];
      *(u16x8*)&dst[((size_t)(b * 8 + h0) * 1024 + n0 + row) * 64 + ch * 8] = v0;
      *(u16x8*)&dst[((size_t)(b * 8 + h0 + 1) * 1024 + n0 + row) * 64 + ch * 8] = v1;
    }
  } else {
    // RP[oc 64][l 128]
#pragma unroll
    for (int xi = 0; xi < 4; ++xi)
#pragma unroll
      for (int yi = 0; yi < 4; ++yi)
#pragma unroll
        for (int r = 0; r < 4; ++r) {
          int lloc = nw + xi * 16 + (lane >> 4) * 4 + r;
          int oc = yi * 16 + (lane & 15);
          float v = acc[xi][yi][r] + bias[m0 + ho * 64 + oc];
          RP[oc * 128 + swz(oc, lloc >> 3) * 8 + (lloc & 7)] = f2bf(v);
        }
    __syncthreads();
    int h0 = (m0 - 1024) >> 6;
#pragma unroll
    for (int uu = 0; uu < 4; ++uu) {
      int unit = uu * 256 + TID, ro = unit >> 4, ch = unit & 15;
      u16x8 v0 = *(const u16x8*)&Al[ro * 128 + swz(ro, ch) * 8];
      u16x8 v1 = *(const u16x8*)&Bl[ro * 128 + swz(ro, ch) * 8];
      *(u16x8*)&vbuf[((size_t)(b * 8 + h0) * 64 + ro) * 1024 + n0 + ch * 8] = v0;
      *(u16x8*)&vbuf[((size_t)(b * 8 + h0 + 1) * 64 + ro) * 1024 + n0 + ch * 8] = v1;
    }
  }
}

// ---------------- MFMA flash attention, 32x32, swapped operands ----------------
// 1D grid 512, XCD-swizzled so each XCD owns 8 bh (K/V L2-resident).
// Double-buffered LDS, global_load_lds staging, ONE barrier per tile.
// Cross-half reductions via permlane32_swap (direction-invariant);
// PV B-frag exchange via known-good shfl_xor select-exchange.
__global__ __launch_bounds__(256) void attn_mfma(const u16* __restrict__ qT,
                                                 const u16* __restrict__ kT,
                                                 const u16* __restrict__ vb,
                                                 u16* __restrict__ aT) {
  __shared__ u16 smem[16384];  // 2 x (Ks[64][64] | Vs[64][64]); repack reuses buf0
  int lin = blockIdx.x;
  int rem = lin >> 3;
  int bh = (lin & 7) * 8 + (rem >> 3);
  int t0 = (rem & 7) * 128;
  int b = bh >> 3, hd = bh & 7;
  int lane = TID & 63, w = TID >> 6;
  int h = lane >> 5, ln = lane & 31;
  int t = t0 + w * 32 + ln;
  const u16* qp = qT + ((size_t)bh * 1024 + t) * 64;
  const u16* kbase = kT + (size_t)bh * 1024 * 64;
  const u16* vbase = vb + (size_t)bh * 64 * 1024;
  bf16x8 qf[4];
#pragma unroll
  for (int kc = 0; kc < 4; ++kc) qf[kc] = ldfrag(qp + kc * 16 + h * 8);
  float m_r = -1e30f, l_r = 0.f;
  f32x16 oacc[2] = {};

  int u0 = TID, u1 = TID + 256;
  int r0 = u0 >> 3, c0 = u0 & 7;
  int r1 = u1 >> 3, c1 = u1 & 7;
  {  // stage tile 0 -> buf0
    u16* Ks = smem;
    u16* Vs = smem + 4096;
    gload16(&kbase[(size_t)r0 * 64 + swz(r0, c0) * 8], &Ks[u0 * 8]);
    gload16(&kbase[(size_t)r1 * 64 + swz(r1, c1) * 8], &Ks[u1 * 8]);
    gload16(&vbase[(size_t)r0 * 1024 + swz(r0, c0) * 8], &Vs[u0 * 8]);
    gload16(&vbase[(size_t)r1 * 1024 + swz(r1, c1) * 8], &Vs[u1 * 8]);
  }
  __syncthreads();
  for (int tile = 0; tile < 16; ++tile) {
    const u16* Ks = smem + (tile & 1) * 8192;
    const u16* Vs = Ks + 4096;
    if (tile < 15) {  // issue next tile into buf^1; lands by end-of-tile barrier
      int sn = (tile + 1) * 64;
      u16* Kn = smem + ((tile + 1) & 1) * 8192;
      u16* Vn = Kn + 4096;
      gload16(&kbase[(size_t)(sn + r0) * 64 + swz(r0, c0) * 8], &Kn[u0 * 8]);
      gload16(&kbase[(size_t)(sn + r1) * 64 + swz(r1, c1) * 8], &Kn[u1 * 8]);
      gload16(&vbase[(size_t)r0 * 1024 + sn + swz(r0, c0) * 8], &Vn[u0 * 8]);
      gload16(&vbase[(size_t)r1 * 1024 + sn + swz(r1, c1) * 8], &Vn[u1 * 8]);
    }
    // S^T[s][t] = sum_c K[s][c] * Q[t][c]  (log2 units; Q pre-scaled by QSC)
    f32x16 sacc[2] = {};
    __builtin_amdgcn_s_setprio(1);
#pragma unroll
    for (int sb = 0; sb < 2; ++sb) {
      int srow = sb * 32 + ln;
#pragma unroll
      for (int kc = 0; kc < 4; ++kc) {
        bf16x8 kf = ldfrag(&Ks[srow * 64 + swz(srow, kc * 2 + h) * 8]);
        sacc[sb] = mfma32(kf, qf[kc], sacc[sb]);
      }
    }
    __builtin_amdgcn_s_setprio(0);
    // online softmax; lane owns row t, 32 of 64 s-values (partner = lane^32)
    float mp[4];
#pragma unroll
    for (int q = 0; q < 4; ++q) {
      mp[q] = fmaxf(fmaxf(sacc[0][q * 4], sacc[0][q * 4 + 1]),
                    fmaxf(sacc[0][q * 4 + 2], sacc[0][q * 4 + 3]));
      mp[q] = fmaxf(mp[q], fmaxf(fmaxf(sacc[1][q * 4], sacc[1][q * 4 + 1]),
                                 fmaxf(sacc[1][q * 4 + 2], sacc[1][q * 4 + 3])));
    }
    float mx = xhalf_max(fmaxf(fmaxf(mp[0], mp[1]), fmaxf(mp[2], mp[3])));
    // defer-max: skip rescale while growth bounded (P <= 2^8)
    bool noresc = (__all(mx <= m_r + 8.f) != 0);
    if (!noresc) {
      float mn = fmaxf(m_r, mx);
      float al = fexp2(m_r - mn);
      m_r = mn;
      l_r *= al;
#pragma unroll
      for (int ca = 0; ca < 2; ++ca)
#pragma unroll
        for (int i = 0; i < 16; ++i) oacc[ca][i] *= al;
    }
    float rp[4] = {0.f, 0.f, 0.f, 0.f};
#pragma unroll
    for (int sb = 0; sb < 2; ++sb)
#pragma unroll
      for (int i = 0; i < 16; ++i) {
        float pv = fexp2(sacc[sb][i] - m_r);
        sacc[sb][i] = pv;
        rp[i & 3] += pv;
      }
    l_r += xhalf_add((rp[0] + rp[1]) + (rp[2] + rp[3]));
    // pack P pairs: W[sb][p4][e] = bf16x2 of s = 32sb + 8p4 + 4h + 2e (+1)
    unsigned W[2][4][2];
#pragma unroll
    for (int sb = 0; sb < 2; ++sb)
#pragma unroll
      for (int p4 = 0; p4 < 4; ++p4)
#pragma unroll
        for (int e = 0; e < 2; ++e)
          W[sb][p4][e] = cvtpk(sacc[sb][p4 * 4 + 2 * e], sacc[sb][p4 * 4 + 2 * e + 1]);
    // per 16-k step m: exchange with lane^32 (known-good), assemble B-frag, PV
#pragma unroll
    for (int m = 0; m < 4; ++m) {
      int sb = m >> 1, q = (m & 1) * 2;
      unsigned a0 = W[sb][q][0], a1 = W[sb][q][1];
      unsigned b0 = W[sb][q + 1][0], b1 = W[sb][q + 1][1];
      unsigned s0w = h ? a0 : b0;
      unsigned s1w = h ? a1 : b1;
      unsigned x0 = (unsigned)__shfl_xor((int)s0w, 32);
      unsigned x1 = (unsigned)__shfl_xor((int)s1w, 32);
      unsigned w0 = h ? x0 : a0;
      unsigned w1 = h ? x1 : a1;
      unsigned w2 = h ? b0 : x0;
      unsigned w3 = h ? b1 : x1;
      uint4 pw = make_uint4(w0, w1, w2, w3);
      bf16x8 pf = __builtin_bit_cast(bf16x8, pw);
      __builtin_amdgcn_s_setprio(1);
#pragma unroll
      for (int ca = 0; ca < 2; ++ca) {
        int crow = ca * 32 + ln;
        bf16x8 vf = ldfrag(&Vs[crow * 64 + swz(crow, m * 2 + h) * 8]);
        oacc[ca] = mfma32(vf, pf, oacc[ca]);  // O^T[c][t]
      }
      __builtin_amdgcn_s_setprio(0);
    }
    __syncthreads();
  }
  // O^T -> LDS [t][c] (swizzled) -> coalesced aT[b][t][hd*64+c]
  float rl = 1.f / l_r;
  int tloc = w * 32 + ln;
#pragma unroll
  for (int ca = 0; ca < 2; ++ca)
#pragma unroll
    for (int p4 = 0; p4 < 4; ++p4)
#pragma unroll
      for (int e = 0; e < 2; ++e) {
        int r = p4 * 4 + e * 2;
        int c = ca * 32 + 8 * p4 + 4 * h + 2 * e;
        unsigned pk = cvtpk(oacc[ca][r] * rl, oacc[ca][r + 1] * rl);
        *(unsigned*)&smem[tloc * 64 + swz(tloc, c >> 3) * 8 + (c & 7)] = pk;
      }
  __syncthreads();
#pragma unroll
  for (int u = 0; u < 4; ++u) {
    int unit = u * 256 + TID;
    int row = unit >> 3, ch = unit & 7;
    u16x8 v = *(const u16x8*)&smem[row * 64 + swz(row, ch) * 8];
    *(u16x8*)&aT[((size_t)b * 1024 + t0 + row) * 512 + hd * 64 + ch * 8] = v;
  }
}

// ---------------- proj GEMM: normal D[o][l], fp32 out + bias + resid ----------------
__global__ __launch_bounds__(256) void proj_gemm(
    const u16* __restrict__ A, const u16* __restrict__ Bt,
    const float* __restrict__ bias, const float* __restrict__ resid,
    float* __restrict__ of) {
  __shared__ u16 Al[8192], Bl[8192];
  int lin = blockIdx.x;           // 256 = 8 XCD chunks x 32 (4 m x 8 n)
  int b = lin & 7;
  int rem = lin >> 3;
  int mi = rem & 3, ni = rem >> 2;
  int m0 = mi * 128, n0 = ni * 128;
  int lane = TID & 63, w = TID >> 6;
  int mw = (w >> 1) * 64, nw = (w & 1) * 64;
  const u16* Bb = Bt + (size_t)b * 1024 * 512;
  f32x4 acc[4][4] = {};
  for (int k0 = 0; k0 < 512; k0 += 64) {
#pragma unroll
    for (int u = 0; u < 4; ++u) {
      int unit = u * 256 + TID, row = unit >> 3, ch = unit & 7;
      gload16(&A[(size_t)(m0 + row) * 512 + k0 + swz(row, ch) * 8], &Al[unit * 8]);
      gload16(&Bb[(size_t)(n0 + row) * 512 + k0 + swz(row, ch) * 8], &Bl[unit * 8]);
    }
    __syncthreads();
    bf16x8 xf[4][2];
#pragma unroll
    for (int xi = 0; xi < 4; ++xi)
#pragma unroll
      for (int kf = 0; kf < 2; ++kf) {
        int row = mw + xi * 16 + (lane & 15);
        int lc = kf * 4 + (lane >> 4);
        xf[xi][kf] = ldfrag(&Al[row * 64 + swz(row, lc) * 8]);
      }
#pragma unroll
    for (int yi = 0; yi < 4; ++yi) {
      int row = nw + yi * 16 + (lane & 15);
      int lc = lane >> 4;
      bf16x8 y0 = ldfrag(&Bl[row * 64 + swz(row, lc) * 8]);
      bf16x8 y1 = ldfrag(&Bl[row * 64 + swz(row, lc + 4) * 8]);
#pragma unroll
      for (int xi = 0; xi < 4; ++xi) {
        acc[xi][yi] = mfma16(xf[xi][0], y0, acc[xi][yi]);
        acc[xi][yi] = mfma16(xf[xi][1], y1, acc[xi][yi]);
      }
    }
    __syncthreads();
  }
#pragma unroll
  for (int xi = 0; xi < 4; ++xi)
#pragma unroll
    for (int yi = 0; yi < 4; ++yi)
#pragma unroll
      for (int r = 0; r < 4; ++r) {
        int o = m0 + mw + xi * 16 + (lane >> 4) * 4 + r;
        int l = n0 + nw + yi * 16 + (lane & 15);
        size_t idx = ((size_t)b * 512 + o) * 1024 + l;
        of[idx] = acc[xi][yi][r] + bias[o] + resid[idx];
      }
}

extern "C" void kernel_launch(void* const* d_in, const int* in_sizes, int n_in,
                              void* d_out, int out_size, void* d_ws, size_t ws_size,
                              hipStream_t stream) {
  const float* x = (const float*)d_in[0];
  const float* gamma = (const float*)d_in[1];
  const float* beta = (const float*)d_in[2];
  const float* w_qkv = (const float*)d_in[3];
  const float* b_qkv = (const float*)d_in[4];
  const float* w_proj = (const float*)d_in[5];
  const float* b_proj = (const float*)d_in[6];
  float* out = (float*)d_out;

  u16* qT = (u16*)d_ws;                    // 64bh*1024*64 = 4194304 u16 (8MB)
  u16* kT = qT + 4194304;                  // 8MB
  u16* vbuf = kT + 4194304;                // 8MB
  u16* aTb = vbuf + 4194304;               // 8MB
  u16* wqb = aTb + 4194304;                // 1.5MB
  u16* wpb = wqb + 786432;                 // 0.5MB
  float* stats = (float*)(wpb + 262144);   // 512 floats
  u16* xnT = (u16*)d_out;                  // 8MB scratch in d_out (overwritten by proj)

  prep_stats<<<dim3(1280), dim3(256), 0, stream>>>(w_qkv, w_proj, wqb, wpb, x, stats);
  gn_apply<<<dim3(32, 8), dim3(256), 0, stream>>>(x, gamma, beta, stats, xnT);
  qkv_gemm<<<dim3(768), dim3(256), 0, stream>>>(wqb, xnT, b_qkv, qT, kT, vbuf);
  attn_mfma<<<dim3(512), dim3(256), 0, stream>>>(qT, kT, vbuf, aTb);
  proj_gemm<<<dim3(256), dim3(256), 0, stream>>>(wpb, aTb, b_proj, x, out);
}